// Round 10
// baseline (180.730 us; speedup 1.0000x reference)
//
#include <hip/hip_runtime.h>
#include <hip/hip_bf16.h>
#include <cstddef>

#define LEAKY 0.01f

typedef short short8 __attribute__((ext_vector_type(8)));
typedef float f32x4 __attribute__((ext_vector_type(4)));

__device__ inline unsigned short bf16b(float f) {
    __hip_bfloat16 h = __float2bfloat16(f);   // RN
    return __builtin_bit_cast(unsigned short, h);
}
__device__ inline float b2f(unsigned short u) {
    unsigned v = (unsigned)u << 16;
    return __builtin_bit_cast(float, v);
}

// ---------- prepack all 4 conv weights into MFMA A-fragment order ----------
__global__ __launch_bounds__(256) void wpack_all(const float* __restrict__ w1,
                                                 const float* __restrict__ w2,
                                                 const float* __restrict__ w3,
                                                 const float* __restrict__ w4,
                                                 unsigned short* __restrict__ wpkAll) {
    const float* srcs[4] = {w1, w2, w3, w4};
    const float* w = srcs[blockIdx.y];
    unsigned short* wpk = wpkAll + blockIdx.y * 36864;
    int idx = blockIdx.x * 256 + threadIdx.x;   // 36864 = 9*4*2*64*8
    int j    = idx & 7;
    int lane = (idx >> 3) & 63;
    int rest = idx >> 9;
    int ks   = rest & 1;
    int mt   = (rest >> 1) & 3;
    int tap  = rest >> 3;
    int co = mt * 16 + (lane & 15);
    int ci = ks * 32 + (lane >> 4) * 8 + j;
    wpk[idx] = bf16b(w[(co * 64 + ci) * 9 + tap]);
}

// ---------- conv strip (NHWC bf16 input) for conv2/conv3 ----------
template<int IH, int IW>
__device__ inline void conv_strip(const unsigned short* __restrict__ inT,
                                  const unsigned short* __restrict__ wpk,
                                  int b, int row, int col0, int lane,
                                  f32x4 acc[4][2]) {
    int n = lane & 15, kg = lane >> 4;
#pragma unroll
    for (int dr = 0; dr < 3; ++dr) {
        int r = 2 * row - 1 + dr;
        if (r < 0) continue;
        const unsigned short* rowp = inT + (((size_t)b * IH + r) * IW) * 64 + kg * 8;
#pragma unroll
        for (int dc = 0; dc < 3; ++dc) {
            int tap = dr * 3 + dc;
            short8 Aw[4][2];
#pragma unroll
            for (int mt = 0; mt < 4; ++mt)
#pragma unroll
                for (int ks = 0; ks < 2; ++ks)
                    Aw[mt][ks] = *(const short8*)(wpk +
                        ((((tap * 4 + mt) * 2 + ks) * 64 + lane) << 3));
            short8 Bx[2][2];
#pragma unroll
            for (int nt = 0; nt < 2; ++nt) {
                int c = 2 * (col0 + nt * 16 + n) - 1 + dc;
                bool ok = c >= 0;
                const unsigned short* p = rowp + (long long)c * 64;
#pragma unroll
                for (int ks = 0; ks < 2; ++ks) {
                    short8 z = {0, 0, 0, 0, 0, 0, 0, 0};
                    if (ok) z = *(const short8*)(p + ks * 32);
                    Bx[nt][ks] = z;
                }
            }
#pragma unroll
            for (int ks = 0; ks < 2; ++ks)
#pragma unroll
                for (int nt = 0; nt < 2; ++nt)
#pragma unroll
                    for (int mt = 0; mt < 4; ++mt)
                        acc[mt][nt] = __builtin_amdgcn_mfma_f32_16x16x32_bf16(
                            Aw[mt][ks], Bx[nt][ks], acc[mt][nt], 0, 0, 0);
        }
    }
}

// epilogue: bias + leaky -> bf16, swizzled 8B stores into LDS tile
__device__ inline void epi_to_lds(f32x4 acc[4][2], const float* __restrict__ bias,
                                  unsigned short* Ls, int pixbase, int lane) {
    int n = lane & 15, kg = lane >> 4;
    float4 bias4[4];
#pragma unroll
    for (int mt = 0; mt < 4; ++mt)
        bias4[mt] = *(const float4*)(bias + mt * 16 + kg * 4);
#pragma unroll
    for (int nt = 0; nt < 2; ++nt) {
        int pix = pixbase + nt * 16 + n;
#pragma unroll
        for (int mt = 0; mt < 4; ++mt) {
            float v0 = acc[mt][nt][0] + bias4[mt].x; v0 = v0 > 0.f ? v0 : LEAKY * v0;
            float v1 = acc[mt][nt][1] + bias4[mt].y; v1 = v1 > 0.f ? v1 : LEAKY * v1;
            float v2 = acc[mt][nt][2] + bias4[mt].z; v2 = v2 > 0.f ? v2 : LEAKY * v2;
            float v3 = acc[mt][nt][3] + bias4[mt].w; v3 = v3 > 0.f ? v3 : LEAKY * v3;
            unsigned lo = bf16b(v0) | ((unsigned)bf16b(v1) << 16);
            unsigned hi = bf16b(v2) | ((unsigned)bf16b(v3) << 16);
            int g = mt * 2 + (kg >> 1);
            *(uint2*)(Ls + pix * 64 + (((g ^ (pix & 7)) << 3) + (kg & 1) * 4)) =
                make_uint2(lo, hi);
        }
    }
}

__device__ inline short8 lds_granule(const unsigned short* Ls, int pix, int cig) {
    return *(const short8*)(Ls + pix * 64 + ((cig ^ (pix & 7)) << 3));
}

// ---------- conv1 fused v2: NCHW f32 -> conv+lrelu -> pool, reg/LDS double-buffer ----------
// block = (b, ohp, half): 2 conv rows x 64 cols -> pooled 1x32.
// Trow[slot 0..128][64 ci] bf16 (slot = input col offset +1; slot 0 = left edge),
// swizzle pos = (ci>>3) ^ ((slot>>2)&7). Staged via packed b32 ci-pair writes.
// One barrier per input row (5 total), loads for row i+1 issued before MFMA of row i.
__global__ __launch_bounds__(256, 4) void conv1f(const float* __restrict__ feat,
                                                 const unsigned short* __restrict__ wpk,
                                                 const float* __restrict__ bias,
                                                 unsigned short* __restrict__ poolT) {
    __shared__ unsigned short buf[2][130 * 64];   // 2 x 16640 B
    unsigned short* Ls = buf[0];                  // epilogue reuse (16 KB)
    int o = blockIdx.x;
    int blk = (o & 7) * 128 + (o >> 3);           // XCD-bijective
    int half = blk & 1, ohp = (blk >> 1) & 63, b = blk >> 7;
    int tid = threadIdx.x, lane = tid & 63, wv = tid >> 6;
    int n = lane & 15, kg = lane >> 4;
    int c0h = half * 64;
    int colw = (wv & 1) * 32;
    int row_wv = 2 * ohp + (wv >> 1);

    int colq = tid & 31, cipq = tid >> 5;         // ci-pair m = cipq + k*8
    const float* fb = feat + (size_t)(b * 64) * 65536;

    f32x4 acc[4][2] = {};
    float4 lo_[4], hi_[4];
    float edge_ = 0.f;

    // LOAD: fetch row r into regs (zeros if r<0; block-uniform)
    auto LOAD = [&](int r) {
#pragma unroll
        for (int k = 0; k < 4; ++k) {
            lo_[k] = make_float4(0.f, 0.f, 0.f, 0.f);
            hi_[k] = make_float4(0.f, 0.f, 0.f, 0.f);
        }
        edge_ = 0.f;
        if (r >= 0) {
            const float* rp = fb + (size_t)r * 256 + 2 * c0h + colq * 4;
#pragma unroll
            for (int k = 0; k < 4; ++k) {
                int m = cipq + k * 8;
                lo_[k] = *(const float4*)(rp + (size_t)(2 * m) * 65536);
                hi_[k] = *(const float4*)(rp + (size_t)(2 * m + 1) * 65536);
            }
            if (tid < 64 && c0h != 0)
                edge_ = fb[(size_t)tid * 65536 + (size_t)r * 256 + 2 * c0h - 1];
        }
    };
    // WRITE: regs -> Trow buffer B (packed b32 per ci-pair)
    auto WRITE = [&](unsigned short* B) {
#pragma unroll
        for (int k = 0; k < 4; ++k) {
            int m = cipq + k * 8;
            int g = m >> 2;                       // granule = (2m)>>3
            int cilow = (2 * m) & 7;              // even
            float fl[4] = {lo_[k].x, lo_[k].y, lo_[k].z, lo_[k].w};
            float fh[4] = {hi_[k].x, hi_[k].y, hi_[k].z, hi_[k].w};
#pragma unroll
            for (int j = 0; j < 4; ++j) {
                int slot = colq * 4 + j + 1;
                int pos = g ^ ((slot >> 2) & 7);
                unsigned pkd = bf16b(fl[j]) | ((unsigned)bf16b(fh[j]) << 16);
                *(unsigned*)(B + slot * 64 + pos * 8 + cilow) = pkd;
            }
        }
        if (tid < 64) {                           // slot 0 (left edge), pos = g
            B[(tid >> 3) * 8 + (tid & 7)] = bf16b(edge_);
        }
    };

    int r0 = 4 * ohp - 1;
    LOAD(r0);
    WRITE(buf[0]);                                // fresh buffer, no barrier needed
    for (int i = 0; i < 5; ++i) {
        if (i < 4) LOAD(r0 + i + 1);              // issue next-row loads early
        __syncthreads();                          // buf[i&1] staged; prev readers done
        int dr = (r0 + i) - 2 * row_wv + 1;
        if (dr >= 0 && dr <= 2) {                 // wave-uniform
            const unsigned short* T = buf[i & 1];
#pragma unroll
            for (int dc = 0; dc < 3; ++dc) {
                int tap = dr * 3 + dc;
                short8 Aw[4][2];
#pragma unroll
                for (int mt = 0; mt < 4; ++mt)
#pragma unroll
                    for (int ks = 0; ks < 2; ++ks)
                        Aw[mt][ks] = *(const short8*)(wpk +
                            ((((tap * 4 + mt) * 2 + ks) * 64 + lane) << 3));
                short8 Bx[2][2];
#pragma unroll
                for (int nt = 0; nt < 2; ++nt) {
                    int slot = 2 * (colw + nt * 16 + n) + dc;   // 0..128
#pragma unroll
                    for (int ks = 0; ks < 2; ++ks) {
                        int pos = (ks * 4 + kg) ^ ((slot >> 2) & 7);
                        Bx[nt][ks] = *(const short8*)(T + slot * 64 + pos * 8);
                    }
                }
#pragma unroll
                for (int ks = 0; ks < 2; ++ks)
#pragma unroll
                    for (int nt = 0; nt < 2; ++nt)
#pragma unroll
                        for (int mt = 0; mt < 4; ++mt)
                            acc[mt][nt] = __builtin_amdgcn_mfma_f32_16x16x32_bf16(
                                Aw[mt][ks], Bx[nt][ks], acc[mt][nt], 0, 0, 0);
            }
        }
        if (i < 4) WRITE(buf[(i + 1) & 1]);
    }

    __syncthreads();                              // last MFMA done before Ls reuse
    epi_to_lds(acc, bias, Ls, (wv >> 1) * 64 + colw, lane);
    __syncthreads();

    int px = tid >> 3, cig = tid & 7;
    float m[8];
#pragma unroll
    for (int j = 0; j < 8; ++j) m[j] = -1e30f;
#pragma unroll
    for (int r = 0; r < 2; ++r)
#pragma unroll
        for (int cx = 0; cx < 2; ++cx) {
            short8 v = lds_granule(Ls, r * 64 + 2 * px + cx, cig);
#pragma unroll
            for (int j = 0; j < 8; ++j)
                m[j] = fmaxf(m[j], b2f((unsigned short)v[j]));
        }
    short8 rv;
#pragma unroll
    for (int j = 0; j < 8; ++j)
        rv[j] = (short)(__builtin_bit_cast(unsigned, m[j]) >> 16);
    *(short8*)(poolT + (((size_t)(b * 64 + ohp) * 64) + half * 32 + px) * 64 + cig * 8) = rv;
}

// ---------- conv2 (64->32) + pool (->16): 128 blocks x 128 thr ----------
__global__ __launch_bounds__(128) void conv2_pool(const unsigned short* __restrict__ inT,
                                                  const unsigned short* __restrict__ wpk,
                                                  const float* __restrict__ bias,
                                                  unsigned short* __restrict__ poolT) {
    __shared__ unsigned short Ls[64 * 64];     // 8 KB
    int o = blockIdx.x;
    int blk = (o & 7) * 16 + (o >> 3);
    int q = blk & 15, b = blk >> 4;
    int tid = threadIdx.x, lane = tid & 63, wv = tid >> 6;

    int row = 2 * q + wv;
    f32x4 acc[4][2] = {};
    conv_strip<64, 64>(inT, wpk, b, row, 0, lane, acc);
    epi_to_lds(acc, bias, Ls, wv * 32, lane);
    __syncthreads();

    int px = tid >> 3, cig = tid & 7;
    float m[8];
#pragma unroll
    for (int j = 0; j < 8; ++j) m[j] = -1e30f;
#pragma unroll
    for (int r = 0; r < 2; ++r)
#pragma unroll
        for (int cx = 0; cx < 2; ++cx) {
            short8 v = lds_granule(Ls, r * 32 + 2 * px + cx, cig);
#pragma unroll
            for (int j = 0; j < 8; ++j)
                m[j] = fmaxf(m[j], b2f((unsigned short)v[j]));
        }
    short8 rv;
#pragma unroll
    for (int j = 0; j < 8; ++j)
        rv[j] = (short)(__builtin_bit_cast(unsigned, m[j]) >> 16);
    *(short8*)(poolT + (((size_t)(b * 16 + q) * 16) + px) * 64 + cig * 8) = rv;
}

// ---------- conv3 (16->8): 4 blocks x 4 waves ----------
__global__ __launch_bounds__(256) void conv3_k(const unsigned short* __restrict__ pool2T,
                                               const unsigned short* __restrict__ wpk3,
                                               const float* __restrict__ bias3,
                                               unsigned short* __restrict__ conv3T) {
    int tid = threadIdx.x, lane = tid & 63, wv = tid >> 6;
    int n = lane & 15, kg = lane >> 4;
    int st = blockIdx.x * 4 + wv;
    f32x4 acc[4][2] = {};
    int bv[2], ohv[2], owv[2];
#pragma unroll
    for (int nt = 0; nt < 2; ++nt) {
        int p = st * 32 + nt * 16 + n;
        bv[nt] = p >> 6; ohv[nt] = (p >> 3) & 7; owv[nt] = p & 7;
    }
#pragma unroll
    for (int dr = 0; dr < 3; ++dr)
#pragma unroll
        for (int dc = 0; dc < 3; ++dc) {
            int tap = dr * 3 + dc;
            short8 Aw[4][2];
#pragma unroll
            for (int mt = 0; mt < 4; ++mt)
#pragma unroll
                for (int ks = 0; ks < 2; ++ks)
                    Aw[mt][ks] = *(const short8*)(wpk3 +
                        ((((tap * 4 + mt) * 2 + ks) * 64 + lane) << 3));
            short8 Bx[2][2];
#pragma unroll
            for (int nt = 0; nt < 2; ++nt) {
                int r = 2 * ohv[nt] - 1 + dr;
                int c = 2 * owv[nt] - 1 + dc;
                bool ok = (r >= 0) && (c >= 0);
                long long off = (((long long)bv[nt] * 16 + r) * 16 + c) * 64 + kg * 8;
#pragma unroll
                for (int ks = 0; ks < 2; ++ks) {
                    short8 z = {0, 0, 0, 0, 0, 0, 0, 0};
                    if (ok) z = *(const short8*)(pool2T + off + ks * 32);
                    Bx[nt][ks] = z;
                }
            }
#pragma unroll
            for (int ks = 0; ks < 2; ++ks)
#pragma unroll
                for (int nt = 0; nt < 2; ++nt)
#pragma unroll
                    for (int mt = 0; mt < 4; ++mt)
                        acc[mt][nt] = __builtin_amdgcn_mfma_f32_16x16x32_bf16(
                            Aw[mt][ks], Bx[nt][ks], acc[mt][nt], 0, 0, 0);
        }
    float4 bias4[4];
#pragma unroll
    for (int mt = 0; mt < 4; ++mt)
        bias4[mt] = *(const float4*)(bias3 + mt * 16 + kg * 4);
#pragma unroll
    for (int nt = 0; nt < 2; ++nt) {
        int pix = st * 32 + nt * 16 + n;
#pragma unroll
        for (int mt = 0; mt < 4; ++mt) {
            float v0 = acc[mt][nt][0] + bias4[mt].x; v0 = v0 > 0.f ? v0 : LEAKY * v0;
            float v1 = acc[mt][nt][1] + bias4[mt].y; v1 = v1 > 0.f ? v1 : LEAKY * v1;
            float v2 = acc[mt][nt][2] + bias4[mt].z; v2 = v2 > 0.f ? v2 : LEAKY * v2;
            float v3 = acc[mt][nt][3] + bias4[mt].w; v3 = v3 > 0.f ? v3 : LEAKY * v3;
            unsigned lo = bf16b(v0) | ((unsigned)bf16b(v1) << 16);
            unsigned hi = bf16b(v2) | ((unsigned)bf16b(v3) << 16);
            *(uint2*)(conv3T + pix * 64 + mt * 16 + kg * 4) = make_uint2(lo, hi);
        }
    }
}

// ---------- conv4 tail: pool3 -> conv4 -> mean -> FC ----------
__global__ __launch_bounds__(256) void conv4_k(const unsigned short* __restrict__ conv3T,
                                               const unsigned short* __restrict__ wpk4,
                                               const float* __restrict__ bias4p,
                                               const float* __restrict__ fcw,
                                               const float* __restrict__ fcb,
                                               float* __restrict__ R) {
    __shared__ unsigned short P3s[128 * 64];
    __shared__ float O4s[32 * 64];
    __shared__ float xsS[512];
    int tid = threadIdx.x, lane = tid & 63, wv = tid >> 6;
    int n = lane & 15, kg = lane >> 4;

    for (int i = 0; i < 4; ++i) {
        int task = i * 256 + tid;
        int cig = task & 7, idx = task >> 3;
        int bb = idx >> 4, y = (idx >> 2) & 3, x = idx & 3;
        float m[8];
#pragma unroll
        for (int j = 0; j < 8; ++j) m[j] = -1e30f;
#pragma unroll
        for (int r = 0; r < 2; ++r)
#pragma unroll
            for (int cx = 0; cx < 2; ++cx) {
                int sp = bb * 64 + (2 * y + r) * 8 + (2 * x + cx);
                short8 v = *(const short8*)(conv3T + sp * 64 + cig * 8);
#pragma unroll
                for (int j = 0; j < 8; ++j)
                    m[j] = fmaxf(m[j], b2f((unsigned short)v[j]));
            }
        short8 rv;
#pragma unroll
        for (int j = 0; j < 8; ++j)
            rv[j] = (short)(__builtin_bit_cast(unsigned, m[j]) >> 16);
        *(short8*)(P3s + idx * 64 + ((cig ^ (idx & 7)) << 3)) = rv;
    }
    __syncthreads();

    if (wv == 0) {
        f32x4 acc[4][2] = {};
        int bv[2], ohv[2], owv[2];
#pragma unroll
        for (int nt = 0; nt < 2; ++nt) {
            int p = nt * 16 + n;
            bv[nt] = p >> 2; ohv[nt] = (p >> 1) & 1; owv[nt] = p & 1;
        }
#pragma unroll
        for (int dr = 0; dr < 3; ++dr)
#pragma unroll
            for (int dc = 0; dc < 3; ++dc) {
                int tap = dr * 3 + dc;
                short8 Aw[4][2];
#pragma unroll
                for (int mt = 0; mt < 4; ++mt)
#pragma unroll
                    for (int ks = 0; ks < 2; ++ks)
                        Aw[mt][ks] = *(const short8*)(wpk4 +
                            ((((tap * 4 + mt) * 2 + ks) * 64 + lane) << 3));
                short8 Bx[2][2];
#pragma unroll
                for (int nt = 0; nt < 2; ++nt) {
                    int r = 2 * ohv[nt] - 1 + dr;
                    int c = 2 * owv[nt] - 1 + dc;
                    bool ok = (r >= 0) && (c >= 0);
                    int pix = bv[nt] * 16 + r * 4 + c;
#pragma unroll
                    for (int ks = 0; ks < 2; ++ks) {
                        short8 z = {0, 0, 0, 0, 0, 0, 0, 0};
                        if (ok) z = *(const short8*)(P3s + pix * 64 +
                                     (((ks * 4 + kg) ^ (pix & 7)) << 3));
                        Bx[nt][ks] = z;
                    }
                }
#pragma unroll
                for (int ks = 0; ks < 2; ++ks)
#pragma unroll
                    for (int nt = 0; nt < 2; ++nt)
#pragma unroll
                        for (int mt = 0; mt < 4; ++mt)
                            acc[mt][nt] = __builtin_amdgcn_mfma_f32_16x16x32_bf16(
                                Aw[mt][ks], Bx[nt][ks], acc[mt][nt], 0, 0, 0);
            }
        float4 bias4[4];
#pragma unroll
        for (int mt = 0; mt < 4; ++mt)
            bias4[mt] = *(const float4*)(bias4p + mt * 16 + kg * 4);
#pragma unroll
        for (int nt = 0; nt < 2; ++nt) {
            int p = nt * 16 + n;
#pragma unroll
            for (int mt = 0; mt < 4; ++mt) {
                float4 ov;
                float v0 = acc[mt][nt][0] + bias4[mt].x; ov.x = v0 > 0.f ? v0 : LEAKY * v0;
                float v1 = acc[mt][nt][1] + bias4[mt].y; ov.y = v1 > 0.f ? v1 : LEAKY * v1;
                float v2 = acc[mt][nt][2] + bias4[mt].z; ov.z = v2 > 0.f ? v2 : LEAKY * v2;
                float v3 = acc[mt][nt][3] + bias4[mt].w; ov.w = v3 > 0.f ? v3 : LEAKY * v3;
                *(float4*)(O4s + p * 64 + mt * 16 + kg * 4) = ov;
            }
        }
    }
    __syncthreads();

    for (int i = tid; i < 512; i += 256) {
        int bb = i >> 6, c = i & 63;
        xsS[i] = 0.25f * (O4s[(4 * bb + 0) * 64 + c] + O4s[(4 * bb + 1) * 64 + c] +
                          O4s[(4 * bb + 2) * 64 + c] + O4s[(4 * bb + 3) * 64 + c]);
    }
    __syncthreads();

#pragma unroll
    for (int k = 0; k < 20; ++k) {
        int o = k * 256 + tid;
        int bb = o / 640, i = o - bb * 640;
        float s = fcb[i];
        const float* wr = fcw + i * 64;
        const float* xb = xsS + bb * 64;
#pragma unroll 8
        for (int c = 0; c < 64; ++c) s += xb[c] * wr[c];
        R[o] = s;
    }
}

// ---------- out = feat + mask, ILP-4 float4 ----------
__global__ __launch_bounds__(256) void final_add_ilp(const float* __restrict__ feat,
                                                     const float* __restrict__ R,
                                                     float* __restrict__ out) {
    int bid = blockIdx.x;
    int q  = bid & 15;
    int bc = bid >> 4;
    int c = bc & 63, b = bc >> 6;
    int tid = threadIdx.x;
    int wq = tid & 63, rg = tid >> 6;
    int w0 = wq * 4;

    const float* Rp = R + (b * 640 + c * 10);
    float r0 = Rp[0], r1 = Rp[1], r2 = Rp[2], r3 = Rp[3], r4 = Rp[4];
    float r5 = Rp[5], r6 = Rp[6], r7 = Rp[7], r8 = Rp[8], r9 = Rp[9];

    float Lw[4], ej[4];
#pragma unroll
    for (int j = 0; j < 4; ++j) {
        Lw[j] = __builtin_amdgcn_logf((float)(w0 + j + 1) * (1.0f / 256.0f));
        ej[j] = (float)(255 - (w0 + j));
    }

    size_t base = ((size_t)(b * 64 + c)) * 65536;
    int h[4];
    float4 f[4];
#pragma unroll
    for (int k = 0; k < 4; ++k) {
        h[k] = q * 16 + k * 4 + rg;
        f[k] = *(const float4*)(feat + base + (size_t)h[k] * 256 + w0);
    }
#pragma unroll
    for (int k = 0; k < 4; ++k) {
        float Lh = __builtin_amdgcn_logf((float)(h[k] + 1) * (1.0f / 256.0f));
        float eh = (float)(255 - h[k]);
        float fv[4] = {f[k].x, f[k].y, f[k].z, f[k].w};
        float ov[4];
#pragma unroll
        for (int j = 0; j < 4; ++j) {
            float a  = __builtin_amdgcn_exp2f(ej[j] * Lh);   // x_h^(255-w)
            float bb = __builtin_amdgcn_exp2f(eh * Lw[j]);   // x_w^(255-h)
            float mask = (r9 + r3)
                       + bb * (r8 + bb * (r7 + bb * r6))
                       + a * ((r5 + bb * (r4 + bb * r3))
                              + a * (r2 + bb * r1 + a * r0));
            ov[j] = fv[j] + mask;
        }
        *(float4*)(out + base + (size_t)h[k] * 256 + w0) =
            make_float4(ov[0], ov[1], ov[2], ov[3]);
    }
}

extern "C" void kernel_launch(void* const* d_in, const int* in_sizes, int n_in,
                              void* d_out, int out_size, void* d_ws, size_t ws_size,
                              hipStream_t stream) {
    const float* feat = (const float*)d_in[0];
    const float* w1   = (const float*)d_in[1];
    const float* b1   = (const float*)d_in[2];
    const float* w2   = (const float*)d_in[3];
    const float* b2   = (const float*)d_in[4];
    const float* w3   = (const float*)d_in[5];
    const float* b3   = (const float*)d_in[6];
    const float* w4   = (const float*)d_in[7];
    const float* b4   = (const float*)d_in[8];
    const float* fcw  = (const float*)d_in[9];
    const float* fcb  = (const float*)d_in[10];
    float* out = (float*)d_out;

    // ws layout (ushort units)
    unsigned short* wsu    = (unsigned short*)d_ws;
    unsigned short* wpkAll = wsu;                        // 147456
    unsigned short* pool1T = wpkAll + 147456;            // 2097152
    unsigned short* pool2T = pool1T + 2097152;           // 131072
    unsigned short* conv3T = pool2T + 131072;            // 32768
    float*          Rm     = (float*)(conv3T + 32768);   // 5120 floats

    wpack_all<<<dim3(144, 4), 256, 0, stream>>>(w1, w2, w3, w4, wpkAll);
    conv1f<<<1024, 256, 0, stream>>>(feat, wpkAll, b1, pool1T);
    conv2_pool<<<128, 128, 0, stream>>>(pool1T, wpkAll + 36864, b2, pool2T);
    conv3_k<<<4, 256, 0, stream>>>(pool2T, wpkAll + 2 * 36864, b3, conv3T);
    conv4_k<<<1, 256, 0, stream>>>(conv3T, wpkAll + 3 * 36864, b4, fcw, fcb, Rm);
    final_add_ilp<<<8192, 256, 0, stream>>>(feat, Rm, out);
}

// Round 11
// 180.329 us; speedup vs baseline: 1.0022x; 1.0022x over previous
//
#include <hip/hip_runtime.h>
#include <hip/hip_bf16.h>
#include <cstddef>

#define LEAKY 0.01f

typedef short short8 __attribute__((ext_vector_type(8)));
typedef float f32x4 __attribute__((ext_vector_type(4)));

__device__ inline unsigned short bf16b(float f) {
    __hip_bfloat16 h = __float2bfloat16(f);   // RN
    return __builtin_bit_cast(unsigned short, h);
}
__device__ inline float b2f(unsigned short u) {
    unsigned v = (unsigned)u << 16;
    return __builtin_bit_cast(float, v);
}

// ---------- prepack all 4 conv weights into MFMA A-fragment order ----------
__global__ __launch_bounds__(256) void wpack_all(const float* __restrict__ w1,
                                                 const float* __restrict__ w2,
                                                 const float* __restrict__ w3,
                                                 const float* __restrict__ w4,
                                                 unsigned short* __restrict__ wpkAll) {
    const float* srcs[4] = {w1, w2, w3, w4};
    const float* w = srcs[blockIdx.y];
    unsigned short* wpk = wpkAll + blockIdx.y * 36864;
    int idx = blockIdx.x * 256 + threadIdx.x;   // 36864 = 9*4*2*64*8
    int j    = idx & 7;
    int lane = (idx >> 3) & 63;
    int rest = idx >> 9;
    int ks   = rest & 1;
    int mt   = (rest >> 1) & 3;
    int tap  = rest >> 3;
    int co = mt * 16 + (lane & 15);
    int ci = ks * 32 + (lane >> 4) * 8 + j;
    wpk[idx] = bf16b(w[(co * 64 + ci) * 9 + tap]);
}

// ---------- conv strip (NHWC bf16 input) for conv2 ----------
template<int IH, int IW>
__device__ inline void conv_strip(const unsigned short* __restrict__ inT,
                                  const unsigned short* __restrict__ wpk,
                                  int b, int row, int col0, int lane,
                                  f32x4 acc[4][2]) {
    int n = lane & 15, kg = lane >> 4;
#pragma unroll
    for (int dr = 0; dr < 3; ++dr) {
        int r = 2 * row - 1 + dr;
        if (r < 0) continue;
        const unsigned short* rowp = inT + (((size_t)b * IH + r) * IW) * 64 + kg * 8;
#pragma unroll
        for (int dc = 0; dc < 3; ++dc) {
            int tap = dr * 3 + dc;
            short8 Aw[4][2];
#pragma unroll
            for (int mt = 0; mt < 4; ++mt)
#pragma unroll
                for (int ks = 0; ks < 2; ++ks)
                    Aw[mt][ks] = *(const short8*)(wpk +
                        ((((tap * 4 + mt) * 2 + ks) * 64 + lane) << 3));
            short8 Bx[2][2];
#pragma unroll
            for (int nt = 0; nt < 2; ++nt) {
                int c = 2 * (col0 + nt * 16 + n) - 1 + dc;
                bool ok = c >= 0;
                const unsigned short* p = rowp + (long long)c * 64;
#pragma unroll
                for (int ks = 0; ks < 2; ++ks) {
                    short8 z = {0, 0, 0, 0, 0, 0, 0, 0};
                    if (ok) z = *(const short8*)(p + ks * 32);
                    Bx[nt][ks] = z;
                }
            }
#pragma unroll
            for (int ks = 0; ks < 2; ++ks)
#pragma unroll
                for (int nt = 0; nt < 2; ++nt)
#pragma unroll
                    for (int mt = 0; mt < 4; ++mt)
                        acc[mt][nt] = __builtin_amdgcn_mfma_f32_16x16x32_bf16(
                            Aw[mt][ks], Bx[nt][ks], acc[mt][nt], 0, 0, 0);
        }
    }
}

// epilogue: bias + leaky -> bf16, swizzled 8B stores into LDS tile
__device__ inline void epi_to_lds(f32x4 acc[4][2], const float* __restrict__ bias,
                                  unsigned short* Ls, int pixbase, int lane) {
    int n = lane & 15, kg = lane >> 4;
    float4 bias4[4];
#pragma unroll
    for (int mt = 0; mt < 4; ++mt)
        bias4[mt] = *(const float4*)(bias + mt * 16 + kg * 4);
#pragma unroll
    for (int nt = 0; nt < 2; ++nt) {
        int pix = pixbase + nt * 16 + n;
#pragma unroll
        for (int mt = 0; mt < 4; ++mt) {
            float v0 = acc[mt][nt][0] + bias4[mt].x; v0 = v0 > 0.f ? v0 : LEAKY * v0;
            float v1 = acc[mt][nt][1] + bias4[mt].y; v1 = v1 > 0.f ? v1 : LEAKY * v1;
            float v2 = acc[mt][nt][2] + bias4[mt].z; v2 = v2 > 0.f ? v2 : LEAKY * v2;
            float v3 = acc[mt][nt][3] + bias4[mt].w; v3 = v3 > 0.f ? v3 : LEAKY * v3;
            unsigned lo = bf16b(v0) | ((unsigned)bf16b(v1) << 16);
            unsigned hi = bf16b(v2) | ((unsigned)bf16b(v3) << 16);
            int g = mt * 2 + (kg >> 1);
            *(uint2*)(Ls + pix * 64 + (((g ^ (pix & 7)) << 3) + (kg & 1) * 4)) =
                make_uint2(lo, hi);
        }
    }
}

__device__ inline short8 lds_granule(const unsigned short* Ls, int pix, int cig) {
    return *(const short8*)(Ls + pix * 64 + ((cig ^ (pix & 7)) << 3));
}

// ---------- conv1 fused v3: NCHW f32 -> conv+lrelu -> pool ----------
// Same as v2 but the barrier sits at the END of each phase, so the global
// loads issued at phase start overlap the MFMA (T14); barrier's vmcnt drain
// lands after the MFMA, right where WRITE needs the data anyway.
__global__ __launch_bounds__(256, 4) void conv1f(const float* __restrict__ feat,
                                                 const unsigned short* __restrict__ wpk,
                                                 const float* __restrict__ bias,
                                                 unsigned short* __restrict__ poolT) {
    __shared__ unsigned short buf[2][130 * 64];   // 2 x 16640 B
    unsigned short* Ls = buf[0];                  // epilogue reuse (16 KB)
    int o = blockIdx.x;
    int blk = (o & 7) * 128 + (o >> 3);           // XCD-bijective
    int half = blk & 1, ohp = (blk >> 1) & 63, b = blk >> 7;
    int tid = threadIdx.x, lane = tid & 63, wv = tid >> 6;
    int n = lane & 15, kg = lane >> 4;
    int c0h = half * 64;
    int colw = (wv & 1) * 32;
    int row_wv = 2 * ohp + (wv >> 1);

    int colq = tid & 31, cipq = tid >> 5;         // ci-pair m = cipq + k*8
    const float* fb = feat + (size_t)(b * 64) * 65536;

    f32x4 acc[4][2] = {};
    float4 lo_[4], hi_[4];
    float edge_ = 0.f;

    auto LOAD = [&](int r) {
#pragma unroll
        for (int k = 0; k < 4; ++k) {
            lo_[k] = make_float4(0.f, 0.f, 0.f, 0.f);
            hi_[k] = make_float4(0.f, 0.f, 0.f, 0.f);
        }
        edge_ = 0.f;
        if (r >= 0) {
            const float* rp = fb + (size_t)r * 256 + 2 * c0h + colq * 4;
#pragma unroll
            for (int k = 0; k < 4; ++k) {
                int m = cipq + k * 8;
                lo_[k] = *(const float4*)(rp + (size_t)(2 * m) * 65536);
                hi_[k] = *(const float4*)(rp + (size_t)(2 * m + 1) * 65536);
            }
            if (tid < 64 && c0h != 0)
                edge_ = fb[(size_t)tid * 65536 + (size_t)r * 256 + 2 * c0h - 1];
        }
    };
    auto WRITE = [&](unsigned short* B) {
#pragma unroll
        for (int k = 0; k < 4; ++k) {
            int m = cipq + k * 8;
            int g = m >> 2;
            int cilow = (2 * m) & 7;
            float fl[4] = {lo_[k].x, lo_[k].y, lo_[k].z, lo_[k].w};
            float fh[4] = {hi_[k].x, hi_[k].y, hi_[k].z, hi_[k].w};
#pragma unroll
            for (int j = 0; j < 4; ++j) {
                int slot = colq * 4 + j + 1;
                int pos = g ^ ((slot >> 2) & 7);
                unsigned pkd = bf16b(fl[j]) | ((unsigned)bf16b(fh[j]) << 16);
                *(unsigned*)(B + slot * 64 + pos * 8 + cilow) = pkd;
            }
        }
        if (tid < 64) {
            B[(tid >> 3) * 8 + (tid & 7)] = bf16b(edge_);
        }
    };

    int r0 = 4 * ohp - 1;
    LOAD(r0);
    WRITE(buf[0]);
    __syncthreads();                              // buf0 staged
    for (int i = 0; i < 5; ++i) {
        if (i < 4) LOAD(r0 + i + 1);              // issue next-row loads
        int dr = (r0 + i) - 2 * row_wv + 1;
        if (dr >= 0 && dr <= 2) {                 // wave-uniform
            const unsigned short* T = buf[i & 1];
#pragma unroll
            for (int dc = 0; dc < 3; ++dc) {
                int tap = dr * 3 + dc;
                short8 Aw[4][2];
#pragma unroll
                for (int mt = 0; mt < 4; ++mt)
#pragma unroll
                    for (int ks = 0; ks < 2; ++ks)
                        Aw[mt][ks] = *(const short8*)(wpk +
                            ((((tap * 4 + mt) * 2 + ks) * 64 + lane) << 3));
                short8 Bx[2][2];
#pragma unroll
                for (int nt = 0; nt < 2; ++nt) {
                    int slot = 2 * (colw + nt * 16 + n) + dc;
#pragma unroll
                    for (int ks = 0; ks < 2; ++ks) {
                        int pos = (ks * 4 + kg) ^ ((slot >> 2) & 7);
                        Bx[nt][ks] = *(const short8*)(T + slot * 64 + pos * 8);
                    }
                }
#pragma unroll
                for (int ks = 0; ks < 2; ++ks)
#pragma unroll
                    for (int nt = 0; nt < 2; ++nt)
#pragma unroll
                        for (int mt = 0; mt < 4; ++mt)
                            acc[mt][nt] = __builtin_amdgcn_mfma_f32_16x16x32_bf16(
                                Aw[mt][ks], Bx[nt][ks], acc[mt][nt], 0, 0, 0);
            }
        }
        if (i < 4) WRITE(buf[(i + 1) & 1]);       // vmcnt drain after MFMA
        __syncthreads();                          // phase boundary
    }

    epi_to_lds(acc, bias, Ls, (wv >> 1) * 64 + colw, lane);
    __syncthreads();

    int px = tid >> 3, cig = tid & 7;
    float m[8];
#pragma unroll
    for (int j = 0; j < 8; ++j) m[j] = -1e30f;
#pragma unroll
    for (int r = 0; r < 2; ++r)
#pragma unroll
        for (int cx = 0; cx < 2; ++cx) {
            short8 v = lds_granule(Ls, r * 64 + 2 * px + cx, cig);
#pragma unroll
            for (int j = 0; j < 8; ++j)
                m[j] = fmaxf(m[j], b2f((unsigned short)v[j]));
        }
    short8 rv;
#pragma unroll
    for (int j = 0; j < 8; ++j)
        rv[j] = (short)(__builtin_bit_cast(unsigned, m[j]) >> 16);
    *(short8*)(poolT + (((size_t)(b * 64 + ohp) * 64) + half * 32 + px) * 64 + cig * 8) = rv;
}

// ---------- conv2 (64->32) + pool (->16): 128 blocks x 128 thr ----------
__global__ __launch_bounds__(128) void conv2_pool(const unsigned short* __restrict__ inT,
                                                  const unsigned short* __restrict__ wpk,
                                                  const float* __restrict__ bias,
                                                  unsigned short* __restrict__ poolT) {
    __shared__ unsigned short Ls[64 * 64];     // 8 KB
    int o = blockIdx.x;
    int blk = (o & 7) * 16 + (o >> 3);
    int q = blk & 15, b = blk >> 4;
    int tid = threadIdx.x, lane = tid & 63, wv = tid >> 6;

    int row = 2 * q + wv;
    f32x4 acc[4][2] = {};
    conv_strip<64, 64>(inT, wpk, b, row, 0, lane, acc);
    epi_to_lds(acc, bias, Ls, wv * 32, lane);
    __syncthreads();

    int px = tid >> 3, cig = tid & 7;
    float m[8];
#pragma unroll
    for (int j = 0; j < 8; ++j) m[j] = -1e30f;
#pragma unroll
    for (int r = 0; r < 2; ++r)
#pragma unroll
        for (int cx = 0; cx < 2; ++cx) {
            short8 v = lds_granule(Ls, r * 32 + 2 * px + cx, cig);
#pragma unroll
            for (int j = 0; j < 8; ++j)
                m[j] = fmaxf(m[j], b2f((unsigned short)v[j]));
        }
    short8 rv;
#pragma unroll
    for (int j = 0; j < 8; ++j)
        rv[j] = (short)(__builtin_bit_cast(unsigned, m[j]) >> 16);
    *(short8*)(poolT + (((size_t)(b * 16 + q) * 16) + px) * 64 + cig * 8) = rv;
}

// ---------- conv3 (16->8): 4 blocks x 4 waves ----------
__global__ __launch_bounds__(256) void conv3_k(const unsigned short* __restrict__ pool2T,
                                               const unsigned short* __restrict__ wpk3,
                                               const float* __restrict__ bias3,
                                               unsigned short* __restrict__ conv3T) {
    int tid = threadIdx.x, lane = tid & 63, wv = tid >> 6;
    int n = lane & 15, kg = lane >> 4;
    int st = blockIdx.x * 4 + wv;
    f32x4 acc[4][2] = {};
    int bv[2], ohv[2], owv[2];
#pragma unroll
    for (int nt = 0; nt < 2; ++nt) {
        int p = st * 32 + nt * 16 + n;
        bv[nt] = p >> 6; ohv[nt] = (p >> 3) & 7; owv[nt] = p & 7;
    }
#pragma unroll
    for (int dr = 0; dr < 3; ++dr)
#pragma unroll
        for (int dc = 0; dc < 3; ++dc) {
            int tap = dr * 3 + dc;
            short8 Aw[4][2];
#pragma unroll
            for (int mt = 0; mt < 4; ++mt)
#pragma unroll
                for (int ks = 0; ks < 2; ++ks)
                    Aw[mt][ks] = *(const short8*)(wpk3 +
                        ((((tap * 4 + mt) * 2 + ks) * 64 + lane) << 3));
            short8 Bx[2][2];
#pragma unroll
            for (int nt = 0; nt < 2; ++nt) {
                int r = 2 * ohv[nt] - 1 + dr;
                int c = 2 * owv[nt] - 1 + dc;
                bool ok = (r >= 0) && (c >= 0);
                long long off = (((long long)bv[nt] * 16 + r) * 16 + c) * 64 + kg * 8;
#pragma unroll
                for (int ks = 0; ks < 2; ++ks) {
                    short8 z = {0, 0, 0, 0, 0, 0, 0, 0};
                    if (ok) z = *(const short8*)(pool2T + off + ks * 32);
                    Bx[nt][ks] = z;
                }
            }
#pragma unroll
            for (int ks = 0; ks < 2; ++ks)
#pragma unroll
                for (int nt = 0; nt < 2; ++nt)
#pragma unroll
                    for (int mt = 0; mt < 4; ++mt)
                        acc[mt][nt] = __builtin_amdgcn_mfma_f32_16x16x32_bf16(
                            Aw[mt][ks], Bx[nt][ks], acc[mt][nt], 0, 0, 0);
        }
    float4 bias4[4];
#pragma unroll
    for (int mt = 0; mt < 4; ++mt)
        bias4[mt] = *(const float4*)(bias3 + mt * 16 + kg * 4);
#pragma unroll
    for (int nt = 0; nt < 2; ++nt) {
        int pix = st * 32 + nt * 16 + n;
#pragma unroll
        for (int mt = 0; mt < 4; ++mt) {
            float v0 = acc[mt][nt][0] + bias4[mt].x; v0 = v0 > 0.f ? v0 : LEAKY * v0;
            float v1 = acc[mt][nt][1] + bias4[mt].y; v1 = v1 > 0.f ? v1 : LEAKY * v1;
            float v2 = acc[mt][nt][2] + bias4[mt].z; v2 = v2 > 0.f ? v2 : LEAKY * v2;
            float v3 = acc[mt][nt][3] + bias4[mt].w; v3 = v3 > 0.f ? v3 : LEAKY * v3;
            unsigned lo = bf16b(v0) | ((unsigned)bf16b(v1) << 16);
            unsigned hi = bf16b(v2) | ((unsigned)bf16b(v3) << 16);
            *(uint2*)(conv3T + pix * 64 + mt * 16 + kg * 4) = make_uint2(lo, hi);
        }
    }
}

// ---------- conv4 tail: pool3 -> conv4 -> mean -> FC ----------
__global__ __launch_bounds__(256) void conv4_k(const unsigned short* __restrict__ conv3T,
                                               const unsigned short* __restrict__ wpk4,
                                               const float* __restrict__ bias4p,
                                               const float* __restrict__ fcw,
                                               const float* __restrict__ fcb,
                                               float* __restrict__ R) {
    __shared__ unsigned short P3s[128 * 64];
    __shared__ float O4s[32 * 64];
    __shared__ float xsS[512];
    int tid = threadIdx.x, lane = tid & 63, wv = tid >> 6;
    int n = lane & 15, kg = lane >> 4;

    for (int i = 0; i < 4; ++i) {
        int task = i * 256 + tid;
        int cig = task & 7, idx = task >> 3;
        int bb = idx >> 4, y = (idx >> 2) & 3, x = idx & 3;
        float m[8];
#pragma unroll
        for (int j = 0; j < 8; ++j) m[j] = -1e30f;
#pragma unroll
        for (int r = 0; r < 2; ++r)
#pragma unroll
            for (int cx = 0; cx < 2; ++cx) {
                int sp = bb * 64 + (2 * y + r) * 8 + (2 * x + cx);
                short8 v = *(const short8*)(conv3T + sp * 64 + cig * 8);
#pragma unroll
                for (int j = 0; j < 8; ++j)
                    m[j] = fmaxf(m[j], b2f((unsigned short)v[j]));
            }
        short8 rv;
#pragma unroll
        for (int j = 0; j < 8; ++j)
            rv[j] = (short)(__builtin_bit_cast(unsigned, m[j]) >> 16);
        *(short8*)(P3s + idx * 64 + ((cig ^ (idx & 7)) << 3)) = rv;
    }
    __syncthreads();

    if (wv == 0) {
        f32x4 acc[4][2] = {};
        int bv[2], ohv[2], owv[2];
#pragma unroll
        for (int nt = 0; nt < 2; ++nt) {
            int p = nt * 16 + n;
            bv[nt] = p >> 2; ohv[nt] = (p >> 1) & 1; owv[nt] = p & 1;
        }
#pragma unroll
        for (int dr = 0; dr < 3; ++dr)
#pragma unroll
            for (int dc = 0; dc < 3; ++dc) {
                int tap = dr * 3 + dc;
                short8 Aw[4][2];
#pragma unroll
                for (int mt = 0; mt < 4; ++mt)
#pragma unroll
                    for (int ks = 0; ks < 2; ++ks)
                        Aw[mt][ks] = *(const short8*)(wpk4 +
                            ((((tap * 4 + mt) * 2 + ks) * 64 + lane) << 3));
                short8 Bx[2][2];
#pragma unroll
                for (int nt = 0; nt < 2; ++nt) {
                    int r = 2 * ohv[nt] - 1 + dr;
                    int c = 2 * owv[nt] - 1 + dc;
                    bool ok = (r >= 0) && (c >= 0);
                    int pix = bv[nt] * 16 + r * 4 + c;
#pragma unroll
                    for (int ks = 0; ks < 2; ++ks) {
                        short8 z = {0, 0, 0, 0, 0, 0, 0, 0};
                        if (ok) z = *(const short8*)(P3s + pix * 64 +
                                     (((ks * 4 + kg) ^ (pix & 7)) << 3));
                        Bx[nt][ks] = z;
                    }
                }
#pragma unroll
                for (int ks = 0; ks < 2; ++ks)
#pragma unroll
                    for (int nt = 0; nt < 2; ++nt)
#pragma unroll
                        for (int mt = 0; mt < 4; ++mt)
                            acc[mt][nt] = __builtin_amdgcn_mfma_f32_16x16x32_bf16(
                                Aw[mt][ks], Bx[nt][ks], acc[mt][nt], 0, 0, 0);
            }
        float4 bias4[4];
#pragma unroll
        for (int mt = 0; mt < 4; ++mt)
            bias4[mt] = *(const float4*)(bias4p + mt * 16 + kg * 4);
#pragma unroll
        for (int nt = 0; nt < 2; ++nt) {
            int p = nt * 16 + n;
#pragma unroll
            for (int mt = 0; mt < 4; ++mt) {
                float4 ov;
                float v0 = acc[mt][nt][0] + bias4[mt].x; ov.x = v0 > 0.f ? v0 : LEAKY * v0;
                float v1 = acc[mt][nt][1] + bias4[mt].y; ov.y = v1 > 0.f ? v1 : LEAKY * v1;
                float v2 = acc[mt][nt][2] + bias4[mt].z; ov.z = v2 > 0.f ? v2 : LEAKY * v2;
                float v3 = acc[mt][nt][3] + bias4[mt].w; ov.w = v3 > 0.f ? v3 : LEAKY * v3;
                *(float4*)(O4s + p * 64 + mt * 16 + kg * 4) = ov;
            }
        }
    }
    __syncthreads();

    for (int i = tid; i < 512; i += 256) {
        int bb = i >> 6, c = i & 63;
        xsS[i] = 0.25f * (O4s[(4 * bb + 0) * 64 + c] + O4s[(4 * bb + 1) * 64 + c] +
                          O4s[(4 * bb + 2) * 64 + c] + O4s[(4 * bb + 3) * 64 + c]);
    }
    __syncthreads();

#pragma unroll
    for (int k = 0; k < 20; ++k) {
        int o = k * 256 + tid;
        int bb = o / 640, i = o - bb * 640;
        float s = fcb[i];
        const float* wr = fcw + i * 64;
        const float* xb = xsS + bb * 64;
#pragma unroll 8
        for (int c = 0; c < 64; ++c) s += xb[c] * wr[c];
        R[o] = s;
    }
}

// ---------- out = feat + mask, ILP-4 float4 ----------
__global__ __launch_bounds__(256) void final_add_ilp(const float* __restrict__ feat,
                                                     const float* __restrict__ R,
                                                     float* __restrict__ out) {
    int bid = blockIdx.x;
    int q  = bid & 15;
    int bc = bid >> 4;
    int c = bc & 63, b = bc >> 6;
    int tid = threadIdx.x;
    int wq = tid & 63, rg = tid >> 6;
    int w0 = wq * 4;

    const float* Rp = R + (b * 640 + c * 10);
    float r0 = Rp[0], r1 = Rp[1], r2 = Rp[2], r3 = Rp[3], r4 = Rp[4];
    float r5 = Rp[5], r6 = Rp[6], r7 = Rp[7], r8 = Rp[8], r9 = Rp[9];

    float Lw[4], ej[4];
#pragma unroll
    for (int j = 0; j < 4; ++j) {
        Lw[j] = __builtin_amdgcn_logf((float)(w0 + j + 1) * (1.0f / 256.0f));
        ej[j] = (float)(255 - (w0 + j));
    }

    size_t base = ((size_t)(b * 64 + c)) * 65536;
    int h[4];
    float4 f[4];
#pragma unroll
    for (int k = 0; k < 4; ++k) {
        h[k] = q * 16 + k * 4 + rg;
        f[k] = *(const float4*)(feat + base + (size_t)h[k] * 256 + w0);
    }
#pragma unroll
    for (int k = 0; k < 4; ++k) {
        float Lh = __builtin_amdgcn_logf((float)(h[k] + 1) * (1.0f / 256.0f));
        float eh = (float)(255 - h[k]);
        float fv[4] = {f[k].x, f[k].y, f[k].z, f[k].w};
        float ov[4];
#pragma unroll
        for (int j = 0; j < 4; ++j) {
            float a  = __builtin_amdgcn_exp2f(ej[j] * Lh);   // x_h^(255-w)
            float bb = __builtin_amdgcn_exp2f(eh * Lw[j]);   // x_w^(255-h)
            float mask = (r9 + r3)
                       + bb * (r8 + bb * (r7 + bb * r6))
                       + a * ((r5 + bb * (r4 + bb * r3))
                              + a * (r2 + bb * r1 + a * r0));
            ov[j] = fv[j] + mask;
        }
        *(float4*)(out + base + (size_t)h[k] * 256 + w0) =
            make_float4(ov[0], ov[1], ov[2], ov[3]);
    }
}

extern "C" void kernel_launch(void* const* d_in, const int* in_sizes, int n_in,
                              void* d_out, int out_size, void* d_ws, size_t ws_size,
                              hipStream_t stream) {
    const float* feat = (const float*)d_in[0];
    const float* w1   = (const float*)d_in[1];
    const float* b1   = (const float*)d_in[2];
    const float* w2   = (const float*)d_in[3];
    const float* b2   = (const float*)d_in[4];
    const float* w3   = (const float*)d_in[5];
    const float* b3   = (const float*)d_in[6];
    const float* w4   = (const float*)d_in[7];
    const float* b4   = (const float*)d_in[8];
    const float* fcw  = (const float*)d_in[9];
    const float* fcb  = (const float*)d_in[10];
    float* out = (float*)d_out;

    // ws layout (ushort units)
    unsigned short* wsu    = (unsigned short*)d_ws;
    unsigned short* wpkAll = wsu;                        // 147456
    unsigned short* pool1T = wpkAll + 147456;            // 2097152
    unsigned short* pool2T = pool1T + 2097152;           // 131072
    unsigned short* conv3T = pool2T + 131072;            // 32768
    float*          Rm     = (float*)(conv3T + 32768);   // 5120 floats

    wpack_all<<<dim3(144, 4), 256, 0, stream>>>(w1, w2, w3, w4, wpkAll);
    conv1f<<<1024, 256, 0, stream>>>(feat, wpkAll, b1, pool1T);
    conv2_pool<<<128, 128, 0, stream>>>(pool1T, wpkAll + 36864, b2, pool2T);
    conv3_k<<<4, 256, 0, stream>>>(pool2T, wpkAll + 2 * 36864, b3, conv3T);
    conv4_k<<<1, 256, 0, stream>>>(conv3T, wpkAll + 3 * 36864, b4, fcw, fcb, Rm);
    final_add_ilp<<<8192, 256, 0, stream>>>(feat, Rm, out);
}

// Round 12
// 157.552 us; speedup vs baseline: 1.1471x; 1.1446x over previous
//
#include <hip/hip_runtime.h>
#include <hip/hip_bf16.h>
#include <cstddef>

#define LEAKY 0.01f

typedef short short8 __attribute__((ext_vector_type(8)));
typedef float f32x4 __attribute__((ext_vector_type(4)));

__device__ inline unsigned short bf16b(float f) {
    __hip_bfloat16 h = __float2bfloat16(f);   // RN
    return __builtin_bit_cast(unsigned short, h);
}
__device__ inline float b2f(unsigned short u) {
    unsigned v = (unsigned)u << 16;
    return __builtin_bit_cast(float, v);
}

// ---------- prepack all 4 conv weights into MFMA A-fragment order ----------
__global__ __launch_bounds__(256) void wpack_all(const float* __restrict__ w1,
                                                 const float* __restrict__ w2,
                                                 const float* __restrict__ w3,
                                                 const float* __restrict__ w4,
                                                 unsigned short* __restrict__ wpkAll) {
    const float* srcs[4] = {w1, w2, w3, w4};
    const float* w = srcs[blockIdx.y];
    unsigned short* wpk = wpkAll + blockIdx.y * 36864;
    int idx = blockIdx.x * 256 + threadIdx.x;   // 36864 = 9*4*2*64*8
    int j    = idx & 7;
    int lane = (idx >> 3) & 63;
    int rest = idx >> 9;
    int ks   = rest & 1;
    int mt   = (rest >> 1) & 3;
    int tap  = rest >> 3;
    int co = mt * 16 + (lane & 15);
    int ci = ks * 32 + (lane >> 4) * 8 + j;
    wpk[idx] = bf16b(w[(co * 64 + ci) * 9 + tap]);
}

// ---------- conv strip (NHWC bf16 input) for conv2 ----------
template<int IH, int IW>
__device__ inline void conv_strip(const unsigned short* __restrict__ inT,
                                  const unsigned short* __restrict__ wpk,
                                  int b, int row, int col0, int lane,
                                  f32x4 acc[4][2]) {
    int n = lane & 15, kg = lane >> 4;
#pragma unroll
    for (int dr = 0; dr < 3; ++dr) {
        int r = 2 * row - 1 + dr;
        if (r < 0) continue;
        const unsigned short* rowp = inT + (((size_t)b * IH + r) * IW) * 64 + kg * 8;
#pragma unroll
        for (int dc = 0; dc < 3; ++dc) {
            int tap = dr * 3 + dc;
            short8 Aw[4][2];
#pragma unroll
            for (int mt = 0; mt < 4; ++mt)
#pragma unroll
                for (int ks = 0; ks < 2; ++ks)
                    Aw[mt][ks] = *(const short8*)(wpk +
                        ((((tap * 4 + mt) * 2 + ks) * 64 + lane) << 3));
            short8 Bx[2][2];
#pragma unroll
            for (int nt = 0; nt < 2; ++nt) {
                int c = 2 * (col0 + nt * 16 + n) - 1 + dc;
                bool ok = c >= 0;
                const unsigned short* p = rowp + (long long)c * 64;
#pragma unroll
                for (int ks = 0; ks < 2; ++ks) {
                    short8 z = {0, 0, 0, 0, 0, 0, 0, 0};
                    if (ok) z = *(const short8*)(p + ks * 32);
                    Bx[nt][ks] = z;
                }
            }
#pragma unroll
            for (int ks = 0; ks < 2; ++ks)
#pragma unroll
                for (int nt = 0; nt < 2; ++nt)
#pragma unroll
                    for (int mt = 0; mt < 4; ++mt)
                        acc[mt][nt] = __builtin_amdgcn_mfma_f32_16x16x32_bf16(
                            Aw[mt][ks], Bx[nt][ks], acc[mt][nt], 0, 0, 0);
        }
    }
}

// epilogue: bias + leaky -> bf16, swizzled 8B stores into LDS tile
__device__ inline void epi_to_lds(f32x4 acc[4][2], const float* __restrict__ bias,
                                  unsigned short* Ls, int pixbase, int lane) {
    int n = lane & 15, kg = lane >> 4;
    float4 bias4[4];
#pragma unroll
    for (int mt = 0; mt < 4; ++mt)
        bias4[mt] = *(const float4*)(bias + mt * 16 + kg * 4);
#pragma unroll
    for (int nt = 0; nt < 2; ++nt) {
        int pix = pixbase + nt * 16 + n;
#pragma unroll
        for (int mt = 0; mt < 4; ++mt) {
            float v0 = acc[mt][nt][0] + bias4[mt].x; v0 = v0 > 0.f ? v0 : LEAKY * v0;
            float v1 = acc[mt][nt][1] + bias4[mt].y; v1 = v1 > 0.f ? v1 : LEAKY * v1;
            float v2 = acc[mt][nt][2] + bias4[mt].z; v2 = v2 > 0.f ? v2 : LEAKY * v2;
            float v3 = acc[mt][nt][3] + bias4[mt].w; v3 = v3 > 0.f ? v3 : LEAKY * v3;
            unsigned lo = bf16b(v0) | ((unsigned)bf16b(v1) << 16);
            unsigned hi = bf16b(v2) | ((unsigned)bf16b(v3) << 16);
            int g = mt * 2 + (kg >> 1);
            *(uint2*)(Ls + pix * 64 + (((g ^ (pix & 7)) << 3) + (kg & 1) * 4)) =
                make_uint2(lo, hi);
        }
    }
}

__device__ inline short8 lds_granule(const unsigned short* Ls, int pix, int cig) {
    return *(const short8*)(Ls + pix * 64 + ((cig ^ (pix & 7)) << 3));
}

// ---------- conv1 fused v4: NCHW f32 -> conv+lrelu -> pool ----------
// Double-buffered, 1 barrier/phase. STAGE merges load->cvt->ds_write so no
// loaded data stays live across the MFMA section (fixes the VGPR-spill that
// produced 47MB of scratch WRITE_SIZE in v2/v3). Compiler is free to
// software-pipeline STAGE's 8 loads against the MFMA with counted waitcnts.
__global__ __launch_bounds__(256, 4) void conv1f(const float* __restrict__ feat,
                                                 const unsigned short* __restrict__ wpk,
                                                 const float* __restrict__ bias,
                                                 unsigned short* __restrict__ poolT) {
    __shared__ unsigned short buf[2][130 * 64];   // 2 x 16640 B
    unsigned short* Ls = buf[0];                  // epilogue reuse (16 KB)
    int o = blockIdx.x;
    int blk = (o & 7) * 128 + (o >> 3);           // XCD-bijective
    int half = blk & 1, ohp = (blk >> 1) & 63, b = blk >> 7;
    int tid = threadIdx.x, lane = tid & 63, wv = tid >> 6;
    int n = lane & 15, kg = lane >> 4;
    int c0h = half * 64;
    int colw = (wv & 1) * 32;
    int row_wv = 2 * ohp + (wv >> 1);

    int colq = tid & 31, cipq = tid >> 5;         // ci-pair m = cipq + k*8
    const float* fb = feat + (size_t)(b * 64) * 65536;

    f32x4 acc[4][2] = {};

    // STAGE row r into buffer B: per-k load -> convert -> packed b32 write.
    auto STAGE = [&](int r, unsigned short* B) {
#pragma unroll
        for (int k = 0; k < 4; ++k) {
            int m = cipq + k * 8;
            float4 lo = make_float4(0.f, 0.f, 0.f, 0.f);
            float4 hi = make_float4(0.f, 0.f, 0.f, 0.f);
            if (r >= 0) {
                const float* rp = fb + (size_t)r * 256 + 2 * c0h + colq * 4;
                lo = *(const float4*)(rp + (size_t)(2 * m) * 65536);
                hi = *(const float4*)(rp + (size_t)(2 * m + 1) * 65536);
            }
            int g = m >> 2;
            int cilow = (2 * m) & 7;
            float fl[4] = {lo.x, lo.y, lo.z, lo.w};
            float fh[4] = {hi.x, hi.y, hi.z, hi.w};
#pragma unroll
            for (int j = 0; j < 4; ++j) {
                int slot = colq * 4 + j + 1;
                int pos = g ^ ((slot >> 2) & 7);
                unsigned pkd = bf16b(fl[j]) | ((unsigned)bf16b(fh[j]) << 16);
                *(unsigned*)(B + slot * 64 + pos * 8 + cilow) = pkd;
            }
        }
        if (tid < 64) {                           // slot 0 = left-halo column
            float v = (r >= 0 && c0h != 0)
                ? fb[(size_t)tid * 65536 + (size_t)r * 256 + 2 * c0h - 1] : 0.f;
            B[(tid >> 3) * 8 + (tid & 7)] = bf16b(v);
        }
    };

    int r0 = 4 * ohp - 1;
    STAGE(r0, buf[0]);
    __syncthreads();                              // buf0 staged
    for (int i = 0; i < 5; ++i) {
        if (i < 4) STAGE(r0 + i + 1, buf[(i + 1) & 1]);   // overlaps MFMA below
        int dr = (r0 + i) - 2 * row_wv + 1;
        if (dr >= 0 && dr <= 2) {                 // wave-uniform
            const unsigned short* T = buf[i & 1];
#pragma unroll
            for (int dc = 0; dc < 3; ++dc) {
                int tap = dr * 3 + dc;
                short8 Aw[4][2];
#pragma unroll
                for (int mt = 0; mt < 4; ++mt)
#pragma unroll
                    for (int ks = 0; ks < 2; ++ks)
                        Aw[mt][ks] = *(const short8*)(wpk +
                            ((((tap * 4 + mt) * 2 + ks) * 64 + lane) << 3));
                short8 Bx[2][2];
#pragma unroll
                for (int nt = 0; nt < 2; ++nt) {
                    int slot = 2 * (colw + nt * 16 + n) + dc;
#pragma unroll
                    for (int ks = 0; ks < 2; ++ks) {
                        int pos = (ks * 4 + kg) ^ ((slot >> 2) & 7);
                        Bx[nt][ks] = *(const short8*)(T + slot * 64 + pos * 8);
                    }
                }
#pragma unroll
                for (int ks = 0; ks < 2; ++ks)
#pragma unroll
                    for (int nt = 0; nt < 2; ++nt)
#pragma unroll
                        for (int mt = 0; mt < 4; ++mt)
                            acc[mt][nt] = __builtin_amdgcn_mfma_f32_16x16x32_bf16(
                                Aw[mt][ks], Bx[nt][ks], acc[mt][nt], 0, 0, 0);
            }
        }
        __syncthreads();                          // phase boundary
    }

    epi_to_lds(acc, bias, Ls, (wv >> 1) * 64 + colw, lane);
    __syncthreads();

    int px = tid >> 3, cig = tid & 7;
    float m[8];
#pragma unroll
    for (int j = 0; j < 8; ++j) m[j] = -1e30f;
#pragma unroll
    for (int r = 0; r < 2; ++r)
#pragma unroll
        for (int cx = 0; cx < 2; ++cx) {
            short8 v = lds_granule(Ls, r * 64 + 2 * px + cx, cig);
#pragma unroll
            for (int j = 0; j < 8; ++j)
                m[j] = fmaxf(m[j], b2f((unsigned short)v[j]));
        }
    short8 rv;
#pragma unroll
    for (int j = 0; j < 8; ++j)
        rv[j] = (short)(__builtin_bit_cast(unsigned, m[j]) >> 16);
    *(short8*)(poolT + (((size_t)(b * 64 + ohp) * 64) + half * 32 + px) * 64 + cig * 8) = rv;
}

// ---------- conv2 (64->32) + pool (->16): 128 blocks x 128 thr ----------
__global__ __launch_bounds__(128) void conv2_pool(const unsigned short* __restrict__ inT,
                                                  const unsigned short* __restrict__ wpk,
                                                  const float* __restrict__ bias,
                                                  unsigned short* __restrict__ poolT) {
    __shared__ unsigned short Ls[64 * 64];     // 8 KB
    int o = blockIdx.x;
    int blk = (o & 7) * 16 + (o >> 3);
    int q = blk & 15, b = blk >> 4;
    int tid = threadIdx.x, lane = tid & 63, wv = tid >> 6;

    int row = 2 * q + wv;
    f32x4 acc[4][2] = {};
    conv_strip<64, 64>(inT, wpk, b, row, 0, lane, acc);
    epi_to_lds(acc, bias, Ls, wv * 32, lane);
    __syncthreads();

    int px = tid >> 3, cig = tid & 7;
    float m[8];
#pragma unroll
    for (int j = 0; j < 8; ++j) m[j] = -1e30f;
#pragma unroll
    for (int r = 0; r < 2; ++r)
#pragma unroll
        for (int cx = 0; cx < 2; ++cx) {
            short8 v = lds_granule(Ls, r * 32 + 2 * px + cx, cig);
#pragma unroll
            for (int j = 0; j < 8; ++j)
                m[j] = fmaxf(m[j], b2f((unsigned short)v[j]));
        }
    short8 rv;
#pragma unroll
    for (int j = 0; j < 8; ++j)
        rv[j] = (short)(__builtin_bit_cast(unsigned, m[j]) >> 16);
    *(short8*)(poolT + (((size_t)(b * 16 + q) * 16) + px) * 64 + cig * 8) = rv;
}

// ---------- conv3 (16->8): 4 blocks x 4 waves ----------
__global__ __launch_bounds__(256) void conv3_k(const unsigned short* __restrict__ pool2T,
                                               const unsigned short* __restrict__ wpk3,
                                               const float* __restrict__ bias3,
                                               unsigned short* __restrict__ conv3T) {
    int tid = threadIdx.x, lane = tid & 63, wv = tid >> 6;
    int n = lane & 15, kg = lane >> 4;
    int st = blockIdx.x * 4 + wv;
    f32x4 acc[4][2] = {};
    int bv[2], ohv[2], owv[2];
#pragma unroll
    for (int nt = 0; nt < 2; ++nt) {
        int p = st * 32 + nt * 16 + n;
        bv[nt] = p >> 6; ohv[nt] = (p >> 3) & 7; owv[nt] = p & 7;
    }
#pragma unroll
    for (int dr = 0; dr < 3; ++dr)
#pragma unroll
        for (int dc = 0; dc < 3; ++dc) {
            int tap = dr * 3 + dc;
            short8 Aw[4][2];
#pragma unroll
            for (int mt = 0; mt < 4; ++mt)
#pragma unroll
                for (int ks = 0; ks < 2; ++ks)
                    Aw[mt][ks] = *(const short8*)(wpk3 +
                        ((((tap * 4 + mt) * 2 + ks) * 64 + lane) << 3));
            short8 Bx[2][2];
#pragma unroll
            for (int nt = 0; nt < 2; ++nt) {
                int r = 2 * ohv[nt] - 1 + dr;
                int c = 2 * owv[nt] - 1 + dc;
                bool ok = (r >= 0) && (c >= 0);
                long long off = (((long long)bv[nt] * 16 + r) * 16 + c) * 64 + kg * 8;
#pragma unroll
                for (int ks = 0; ks < 2; ++ks) {
                    short8 z = {0, 0, 0, 0, 0, 0, 0, 0};
                    if (ok) z = *(const short8*)(pool2T + off + ks * 32);
                    Bx[nt][ks] = z;
                }
            }
#pragma unroll
            for (int ks = 0; ks < 2; ++ks)
#pragma unroll
                for (int nt = 0; nt < 2; ++nt)
#pragma unroll
                    for (int mt = 0; mt < 4; ++mt)
                        acc[mt][nt] = __builtin_amdgcn_mfma_f32_16x16x32_bf16(
                            Aw[mt][ks], Bx[nt][ks], acc[mt][nt], 0, 0, 0);
        }
    float4 bias4[4];
#pragma unroll
    for (int mt = 0; mt < 4; ++mt)
        bias4[mt] = *(const float4*)(bias3 + mt * 16 + kg * 4);
#pragma unroll
    for (int nt = 0; nt < 2; ++nt) {
        int pix = st * 32 + nt * 16 + n;
#pragma unroll
        for (int mt = 0; mt < 4; ++mt) {
            float v0 = acc[mt][nt][0] + bias4[mt].x; v0 = v0 > 0.f ? v0 : LEAKY * v0;
            float v1 = acc[mt][nt][1] + bias4[mt].y; v1 = v1 > 0.f ? v1 : LEAKY * v1;
            float v2 = acc[mt][nt][2] + bias4[mt].z; v2 = v2 > 0.f ? v2 : LEAKY * v2;
            float v3 = acc[mt][nt][3] + bias4[mt].w; v3 = v3 > 0.f ? v3 : LEAKY * v3;
            unsigned lo = bf16b(v0) | ((unsigned)bf16b(v1) << 16);
            unsigned hi = bf16b(v2) | ((unsigned)bf16b(v3) << 16);
            *(uint2*)(conv3T + pix * 64 + mt * 16 + kg * 4) = make_uint2(lo, hi);
        }
    }
}

// ---------- conv4 tail: pool3 -> conv4 -> mean -> FC ----------
__global__ __launch_bounds__(256) void conv4_k(const unsigned short* __restrict__ conv3T,
                                               const unsigned short* __restrict__ wpk4,
                                               const float* __restrict__ bias4p,
                                               const float* __restrict__ fcw,
                                               const float* __restrict__ fcb,
                                               float* __restrict__ R) {
    __shared__ unsigned short P3s[128 * 64];
    __shared__ float O4s[32 * 64];
    __shared__ float xsS[512];
    int tid = threadIdx.x, lane = tid & 63, wv = tid >> 6;
    int n = lane & 15, kg = lane >> 4;

    for (int i = 0; i < 4; ++i) {
        int task = i * 256 + tid;
        int cig = task & 7, idx = task >> 3;
        int bb = idx >> 4, y = (idx >> 2) & 3, x = idx & 3;
        float m[8];
#pragma unroll
        for (int j = 0; j < 8; ++j) m[j] = -1e30f;
#pragma unroll
        for (int r = 0; r < 2; ++r)
#pragma unroll
            for (int cx = 0; cx < 2; ++cx) {
                int sp = bb * 64 + (2 * y + r) * 8 + (2 * x + cx);
                short8 v = *(const short8*)(conv3T + sp * 64 + cig * 8);
#pragma unroll
                for (int j = 0; j < 8; ++j)
                    m[j] = fmaxf(m[j], b2f((unsigned short)v[j]));
            }
        short8 rv;
#pragma unroll
        for (int j = 0; j < 8; ++j)
            rv[j] = (short)(__builtin_bit_cast(unsigned, m[j]) >> 16);
        *(short8*)(P3s + idx * 64 + ((cig ^ (idx & 7)) << 3)) = rv;
    }
    __syncthreads();

    if (wv == 0) {
        f32x4 acc[4][2] = {};
        int bv[2], ohv[2], owv[2];
#pragma unroll
        for (int nt = 0; nt < 2; ++nt) {
            int p = nt * 16 + n;
            bv[nt] = p >> 2; ohv[nt] = (p >> 1) & 1; owv[nt] = p & 1;
        }
#pragma unroll
        for (int dr = 0; dr < 3; ++dr)
#pragma unroll
            for (int dc = 0; dc < 3; ++dc) {
                int tap = dr * 3 + dc;
                short8 Aw[4][2];
#pragma unroll
                for (int mt = 0; mt < 4; ++mt)
#pragma unroll
                    for (int ks = 0; ks < 2; ++ks)
                        Aw[mt][ks] = *(const short8*)(wpk4 +
                            ((((tap * 4 + mt) * 2 + ks) * 64 + lane) << 3));
                short8 Bx[2][2];
#pragma unroll
                for (int nt = 0; nt < 2; ++nt) {
                    int r = 2 * ohv[nt] - 1 + dr;
                    int c = 2 * owv[nt] - 1 + dc;
                    bool ok = (r >= 0) && (c >= 0);
                    int pix = bv[nt] * 16 + r * 4 + c;
#pragma unroll
                    for (int ks = 0; ks < 2; ++ks) {
                        short8 z = {0, 0, 0, 0, 0, 0, 0, 0};
                        if (ok) z = *(const short8*)(P3s + pix * 64 +
                                     (((ks * 4 + kg) ^ (pix & 7)) << 3));
                        Bx[nt][ks] = z;
                    }
                }
#pragma unroll
                for (int ks = 0; ks < 2; ++ks)
#pragma unroll
                    for (int nt = 0; nt < 2; ++nt)
#pragma unroll
                        for (int mt = 0; mt < 4; ++mt)
                            acc[mt][nt] = __builtin_amdgcn_mfma_f32_16x16x32_bf16(
                                Aw[mt][ks], Bx[nt][ks], acc[mt][nt], 0, 0, 0);
            }
        float4 bias4[4];
#pragma unroll
        for (int mt = 0; mt < 4; ++mt)
            bias4[mt] = *(const float4*)(bias4p + mt * 16 + kg * 4);
#pragma unroll
        for (int nt = 0; nt < 2; ++nt) {
            int p = nt * 16 + n;
#pragma unroll
            for (int mt = 0; mt < 4; ++mt) {
                float4 ov;
                float v0 = acc[mt][nt][0] + bias4[mt].x; ov.x = v0 > 0.f ? v0 : LEAKY * v0;
                float v1 = acc[mt][nt][1] + bias4[mt].y; ov.y = v1 > 0.f ? v1 : LEAKY * v1;
                float v2 = acc[mt][nt][2] + bias4[mt].z; ov.z = v2 > 0.f ? v2 : LEAKY * v2;
                float v3 = acc[mt][nt][3] + bias4[mt].w; ov.w = v3 > 0.f ? v3 : LEAKY * v3;
                *(float4*)(O4s + p * 64 + mt * 16 + kg * 4) = ov;
            }
        }
    }
    __syncthreads();

    for (int i = tid; i < 512; i += 256) {
        int bb = i >> 6, c = i & 63;
        xsS[i] = 0.25f * (O4s[(4 * bb + 0) * 64 + c] + O4s[(4 * bb + 1) * 64 + c] +
                          O4s[(4 * bb + 2) * 64 + c] + O4s[(4 * bb + 3) * 64 + c]);
    }
    __syncthreads();

#pragma unroll
    for (int k = 0; k < 20; ++k) {
        int o = k * 256 + tid;
        int bb = o / 640, i = o - bb * 640;
        float s = fcb[i];
        const float* wr = fcw + i * 64;
        const float* xb = xsS + bb * 64;
#pragma unroll 8
        for (int c = 0; c < 64; ++c) s += xb[c] * wr[c];
        R[o] = s;
    }
}

// ---------- out = feat + mask, ILP-4 float4 ----------
__global__ __launch_bounds__(256) void final_add_ilp(const float* __restrict__ feat,
                                                     const float* __restrict__ R,
                                                     float* __restrict__ out) {
    int bid = blockIdx.x;
    int q  = bid & 15;
    int bc = bid >> 4;
    int c = bc & 63, b = bc >> 6;
    int tid = threadIdx.x;
    int wq = tid & 63, rg = tid >> 6;
    int w0 = wq * 4;

    const float* Rp = R + (b * 640 + c * 10);
    float r0 = Rp[0], r1 = Rp[1], r2 = Rp[2], r3 = Rp[3], r4 = Rp[4];
    float r5 = Rp[5], r6 = Rp[6], r7 = Rp[7], r8 = Rp[8], r9 = Rp[9];

    float Lw[4], ej[4];
#pragma unroll
    for (int j = 0; j < 4; ++j) {
        Lw[j] = __builtin_amdgcn_logf((float)(w0 + j + 1) * (1.0f / 256.0f));
        ej[j] = (float)(255 - (w0 + j));
    }

    size_t base = ((size_t)(b * 64 + c)) * 65536;
    int h[4];
    float4 f[4];
#pragma unroll
    for (int k = 0; k < 4; ++k) {
        h[k] = q * 16 + k * 4 + rg;
        f[k] = *(const float4*)(feat + base + (size_t)h[k] * 256 + w0);
    }
#pragma unroll
    for (int k = 0; k < 4; ++k) {
        float Lh = __builtin_amdgcn_logf((float)(h[k] + 1) * (1.0f / 256.0f));
        float eh = (float)(255 - h[k]);
        float fv[4] = {f[k].x, f[k].y, f[k].z, f[k].w};
        float ov[4];
#pragma unroll
        for (int j = 0; j < 4; ++j) {
            float a  = __builtin_amdgcn_exp2f(ej[j] * Lh);   // x_h^(255-w)
            float bb = __builtin_amdgcn_exp2f(eh * Lw[j]);   // x_w^(255-h)
            float mask = (r9 + r3)
                       + bb * (r8 + bb * (r7 + bb * r6))
                       + a * ((r5 + bb * (r4 + bb * r3))
                              + a * (r2 + bb * r1 + a * r0));
            ov[j] = fv[j] + mask;
        }
        *(float4*)(out + base + (size_t)h[k] * 256 + w0) =
            make_float4(ov[0], ov[1], ov[2], ov[3]);
    }
}

extern "C" void kernel_launch(void* const* d_in, const int* in_sizes, int n_in,
                              void* d_out, int out_size, void* d_ws, size_t ws_size,
                              hipStream_t stream) {
    const float* feat = (const float*)d_in[0];
    const float* w1   = (const float*)d_in[1];
    const float* b1   = (const float*)d_in[2];
    const float* w2   = (const float*)d_in[3];
    const float* b2   = (const float*)d_in[4];
    const float* w3   = (const float*)d_in[5];
    const float* b3   = (const float*)d_in[6];
    const float* w4   = (const float*)d_in[7];
    const float* b4   = (const float*)d_in[8];
    const float* fcw  = (const float*)d_in[9];
    const float* fcb  = (const float*)d_in[10];
    float* out = (float*)d_out;

    // ws layout (ushort units)
    unsigned short* wsu    = (unsigned short*)d_ws;
    unsigned short* wpkAll = wsu;                        // 147456
    unsigned short* pool1T = wpkAll + 147456;            // 2097152
    unsigned short* pool2T = pool1T + 2097152;           // 131072
    unsigned short* conv3T = pool2T + 131072;            // 32768
    float*          Rm     = (float*)(conv3T + 32768);   // 5120 floats

    wpack_all<<<dim3(144, 4), 256, 0, stream>>>(w1, w2, w3, w4, wpkAll);
    conv1f<<<1024, 256, 0, stream>>>(feat, wpkAll, b1, pool1T);
    conv2_pool<<<128, 128, 0, stream>>>(pool1T, wpkAll + 36864, b2, pool2T);
    conv3_k<<<4, 256, 0, stream>>>(pool2T, wpkAll + 2 * 36864, b3, conv3T);
    conv4_k<<<1, 256, 0, stream>>>(conv3T, wpkAll + 3 * 36864, b4, fcw, fcb, Rm);
    final_add_ilp<<<8192, 256, 0, stream>>>(feat, Rm, out);
}

// Round 13
// 142.912 us; speedup vs baseline: 1.2646x; 1.1024x over previous
//
#include <hip/hip_runtime.h>
#include <hip/hip_bf16.h>
#include <cstddef>

#define LEAKY 0.01f

typedef short short8 __attribute__((ext_vector_type(8)));
typedef float f32x4 __attribute__((ext_vector_type(4)));

__device__ inline unsigned short bf16b(float f) {
    __hip_bfloat16 h = __float2bfloat16(f);   // RN
    return __builtin_bit_cast(unsigned short, h);
}
__device__ inline float b2f(unsigned short u) {
    unsigned v = (unsigned)u << 16;
    return __builtin_bit_cast(float, v);
}

// ---------- prepack all 4 conv weights into MFMA A-fragment order ----------
__global__ __launch_bounds__(256) void wpack_all(const float* __restrict__ w1,
                                                 const float* __restrict__ w2,
                                                 const float* __restrict__ w3,
                                                 const float* __restrict__ w4,
                                                 unsigned short* __restrict__ wpkAll) {
    const float* srcs[4] = {w1, w2, w3, w4};
    const float* w = srcs[blockIdx.y];
    unsigned short* wpk = wpkAll + blockIdx.y * 36864;
    int idx = blockIdx.x * 256 + threadIdx.x;   // 36864 = 9*4*2*64*8
    int j    = idx & 7;
    int lane = (idx >> 3) & 63;
    int rest = idx >> 9;
    int ks   = rest & 1;
    int mt   = (rest >> 1) & 3;
    int tap  = rest >> 3;
    int co = mt * 16 + (lane & 15);
    int ci = ks * 32 + (lane >> 4) * 8 + j;
    wpk[idx] = bf16b(w[(co * 64 + ci) * 9 + tap]);
}

// ---------- conv strip (NHWC bf16 input) for conv2 ----------
template<int IH, int IW>
__device__ inline void conv_strip(const unsigned short* __restrict__ inT,
                                  const unsigned short* __restrict__ wpk,
                                  int b, int row, int col0, int lane,
                                  f32x4 acc[4][2]) {
    int n = lane & 15, kg = lane >> 4;
#pragma unroll
    for (int dr = 0; dr < 3; ++dr) {
        int r = 2 * row - 1 + dr;
        if (r < 0) continue;
        const unsigned short* rowp = inT + (((size_t)b * IH + r) * IW) * 64 + kg * 8;
#pragma unroll
        for (int dc = 0; dc < 3; ++dc) {
            int tap = dr * 3 + dc;
            short8 Aw[4][2];
#pragma unroll
            for (int mt = 0; mt < 4; ++mt)
#pragma unroll
                for (int ks = 0; ks < 2; ++ks)
                    Aw[mt][ks] = *(const short8*)(wpk +
                        ((((tap * 4 + mt) * 2 + ks) * 64 + lane) << 3));
            short8 Bx[2][2];
#pragma unroll
            for (int nt = 0; nt < 2; ++nt) {
                int c = 2 * (col0 + nt * 16 + n) - 1 + dc;
                bool ok = c >= 0;
                const unsigned short* p = rowp + (long long)c * 64;
#pragma unroll
                for (int ks = 0; ks < 2; ++ks) {
                    short8 z = {0, 0, 0, 0, 0, 0, 0, 0};
                    if (ok) z = *(const short8*)(p + ks * 32);
                    Bx[nt][ks] = z;
                }
            }
#pragma unroll
            for (int ks = 0; ks < 2; ++ks)
#pragma unroll
                for (int nt = 0; nt < 2; ++nt)
#pragma unroll
                    for (int mt = 0; mt < 4; ++mt)
                        acc[mt][nt] = __builtin_amdgcn_mfma_f32_16x16x32_bf16(
                            Aw[mt][ks], Bx[nt][ks], acc[mt][nt], 0, 0, 0);
        }
    }
}

// epilogue: bias + leaky -> bf16, swizzled 8B stores into LDS tile
__device__ inline void epi_to_lds(f32x4 acc[4][2], const float* __restrict__ bias,
                                  unsigned short* Ls, int pixbase, int lane) {
    int n = lane & 15, kg = lane >> 4;
    float4 bias4[4];
#pragma unroll
    for (int mt = 0; mt < 4; ++mt)
        bias4[mt] = *(const float4*)(bias + mt * 16 + kg * 4);
#pragma unroll
    for (int nt = 0; nt < 2; ++nt) {
        int pix = pixbase + nt * 16 + n;
#pragma unroll
        for (int mt = 0; mt < 4; ++mt) {
            float v0 = acc[mt][nt][0] + bias4[mt].x; v0 = v0 > 0.f ? v0 : LEAKY * v0;
            float v1 = acc[mt][nt][1] + bias4[mt].y; v1 = v1 > 0.f ? v1 : LEAKY * v1;
            float v2 = acc[mt][nt][2] + bias4[mt].z; v2 = v2 > 0.f ? v2 : LEAKY * v2;
            float v3 = acc[mt][nt][3] + bias4[mt].w; v3 = v3 > 0.f ? v3 : LEAKY * v3;
            unsigned lo = bf16b(v0) | ((unsigned)bf16b(v1) << 16);
            unsigned hi = bf16b(v2) | ((unsigned)bf16b(v3) << 16);
            int g = mt * 2 + (kg >> 1);
            *(uint2*)(Ls + pix * 64 + (((g ^ (pix & 7)) << 3) + (kg & 1) * 4)) =
                make_uint2(lo, hi);
        }
    }
}

__device__ inline short8 lds_granule(const unsigned short* Ls, int pix, int cig) {
    return *(const short8*)(Ls + pix * 64 + ((cig ^ (pix & 7)) << 3));
}

// ---------- conv1 fused (round-9 structure): NCHW f32 -> conv+lrelu -> pool ----------
// Single Trow tile (16.6 KB LDS), 2 barriers/row, scalar u16 staged writes —
// the empirically fastest variant (r9 ≈ 67 µs vs r10-r12's 82-97). Change vs
// r9: the pool tile REUSES Trow (one extra barrier) -> LDS 33 -> 16.6 KB,
// occupancy 4 -> 5 blocks/CU (96 unified regs <= 512/5) on a latency-bound kernel.
__global__ __launch_bounds__(256, 4) void conv1f(const float* __restrict__ feat,
                                                 const unsigned short* __restrict__ wpk,
                                                 const float* __restrict__ bias,
                                                 unsigned short* __restrict__ poolT) {
    __shared__ unsigned short Trow[130 * 64];   // 16640 B; reused as pool tile
    int o = blockIdx.x;
    int blk = (o & 7) * 128 + (o >> 3);         // XCD-bijective
    int half = blk & 1, ohp = (blk >> 1) & 63, b = blk >> 7;
    int tid = threadIdx.x, lane = tid & 63, wv = tid >> 6;
    int n = lane & 15, kg = lane >> 4;
    int c0h = half * 64;                        // block's output-col base
    int colw = (wv & 1) * 32;                   // wave's col offset in block
    int row_wv = 2 * ohp + (wv >> 1);           // wave's conv output row

    f32x4 acc[4][2] = {};

    int ci0 = tid >> 5, colq = tid & 31;
    const float* fb = feat + (size_t)(b * 64) * 65536;

    for (int r = 4 * ohp - 1; r <= 4 * ohp + 3; ++r) {
        if (r < 0) continue;                    // block-uniform
        __syncthreads();                        // Trow free of prior readers
        // ---- stage row r: bulk cols [2*c0h, 2*c0h+128), coalesced 512B/wave ----
#pragma unroll
        for (int k = 0; k < 8; ++k) {
            int cci = ci0 + k * 8;
            float4 f = *(const float4*)(fb + (size_t)cci * 65536 +
                                        (size_t)r * 256 + 2 * c0h + colq * 4);
            float fv[4] = {f.x, f.y, f.z, f.w};
#pragma unroll
            for (int j = 0; j < 4; ++j) {
                int slot = colq * 4 + j + 1;
                int pos = (cci >> 3) ^ ((slot >> 2) & 7);
                Trow[slot * 64 + pos * 8 + (cci & 7)] = bf16b(fv[j]);
            }
        }
        // ---- edge slot 0 = input col 2*c0h-1 (zeros when half==0) ----
        if (tid < 64) {
            float v = (c0h == 0) ? 0.f
                : fb[(size_t)tid * 65536 + (size_t)r * 256 + 2 * c0h - 1];
            Trow[(tid >> 3) * 8 + (tid & 7)] = bf16b(v);
        }
        __syncthreads();
        // ---- MFMA: this wave uses row r iff dr in [0,2] ----
        int dr = r - 2 * row_wv + 1;
        if (dr < 0 || dr > 2) continue;         // wave-uniform
#pragma unroll
        for (int dc = 0; dc < 3; ++dc) {
            int tap = dr * 3 + dc;
            short8 Aw[4][2];
#pragma unroll
            for (int mt = 0; mt < 4; ++mt)
#pragma unroll
                for (int ks = 0; ks < 2; ++ks)
                    Aw[mt][ks] = *(const short8*)(wpk +
                        ((((tap * 4 + mt) * 2 + ks) * 64 + lane) << 3));
            short8 Bx[2][2];
#pragma unroll
            for (int nt = 0; nt < 2; ++nt) {
                int slot = 2 * (colw + nt * 16 + n) + dc;   // 0..128
#pragma unroll
                for (int ks = 0; ks < 2; ++ks) {
                    int g = ks * 4 + kg;
                    int pos = g ^ ((slot >> 2) & 7);
                    Bx[nt][ks] = *(const short8*)(Trow + slot * 64 + pos * 8);
                }
            }
#pragma unroll
            for (int ks = 0; ks < 2; ++ks)
#pragma unroll
                for (int nt = 0; nt < 2; ++nt)
#pragma unroll
                    for (int mt = 0; mt < 4; ++mt)
                        acc[mt][nt] = __builtin_amdgcn_mfma_f32_16x16x32_bf16(
                            Aw[mt][ks], Bx[nt][ks], acc[mt][nt], 0, 0, 0);
        }
    }

    // ---- epilogue + pool, reusing Trow as the tile ----
    __syncthreads();                            // all MFMA reads of Trow done
    epi_to_lds(acc, bias, Trow, (wv >> 1) * 64 + colw, lane);
    __syncthreads();

    int px = tid >> 3, cig = tid & 7;
    float m[8];
#pragma unroll
    for (int j = 0; j < 8; ++j) m[j] = -1e30f;
#pragma unroll
    for (int r = 0; r < 2; ++r)
#pragma unroll
        for (int cx = 0; cx < 2; ++cx) {
            short8 v = lds_granule(Trow, r * 64 + 2 * px + cx, cig);
#pragma unroll
            for (int j = 0; j < 8; ++j)
                m[j] = fmaxf(m[j], b2f((unsigned short)v[j]));
        }
    short8 rv;
#pragma unroll
    for (int j = 0; j < 8; ++j)
        rv[j] = (short)(__builtin_bit_cast(unsigned, m[j]) >> 16);
    *(short8*)(poolT + (((size_t)(b * 64 + ohp) * 64) + half * 32 + px) * 64 + cig * 8) = rv;
}

// ---------- conv2 (64->32) + pool (->16): 128 blocks x 128 thr ----------
__global__ __launch_bounds__(128) void conv2_pool(const unsigned short* __restrict__ inT,
                                                  const unsigned short* __restrict__ wpk,
                                                  const float* __restrict__ bias,
                                                  unsigned short* __restrict__ poolT) {
    __shared__ unsigned short Ls[64 * 64];     // 8 KB
    int o = blockIdx.x;
    int blk = (o & 7) * 16 + (o >> 3);
    int q = blk & 15, b = blk >> 4;
    int tid = threadIdx.x, lane = tid & 63, wv = tid >> 6;

    int row = 2 * q + wv;
    f32x4 acc[4][2] = {};
    conv_strip<64, 64>(inT, wpk, b, row, 0, lane, acc);
    epi_to_lds(acc, bias, Ls, wv * 32, lane);
    __syncthreads();

    int px = tid >> 3, cig = tid & 7;
    float m[8];
#pragma unroll
    for (int j = 0; j < 8; ++j) m[j] = -1e30f;
#pragma unroll
    for (int r = 0; r < 2; ++r)
#pragma unroll
        for (int cx = 0; cx < 2; ++cx) {
            short8 v = lds_granule(Ls, r * 32 + 2 * px + cx, cig);
#pragma unroll
            for (int j = 0; j < 8; ++j)
                m[j] = fmaxf(m[j], b2f((unsigned short)v[j]));
        }
    short8 rv;
#pragma unroll
    for (int j = 0; j < 8; ++j)
        rv[j] = (short)(__builtin_bit_cast(unsigned, m[j]) >> 16);
    *(short8*)(poolT + (((size_t)(b * 16 + q) * 16) + px) * 64 + cig * 8) = rv;
}

// ---------- conv3 (16->8): 4 blocks x 4 waves ----------
__global__ __launch_bounds__(256) void conv3_k(const unsigned short* __restrict__ pool2T,
                                               const unsigned short* __restrict__ wpk3,
                                               const float* __restrict__ bias3,
                                               unsigned short* __restrict__ conv3T) {
    int tid = threadIdx.x, lane = tid & 63, wv = tid >> 6;
    int n = lane & 15, kg = lane >> 4;
    int st = blockIdx.x * 4 + wv;
    f32x4 acc[4][2] = {};
    int bv[2], ohv[2], owv[2];
#pragma unroll
    for (int nt = 0; nt < 2; ++nt) {
        int p = st * 32 + nt * 16 + n;
        bv[nt] = p >> 6; ohv[nt] = (p >> 3) & 7; owv[nt] = p & 7;
    }
#pragma unroll
    for (int dr = 0; dr < 3; ++dr)
#pragma unroll
        for (int dc = 0; dc < 3; ++dc) {
            int tap = dr * 3 + dc;
            short8 Aw[4][2];
#pragma unroll
            for (int mt = 0; mt < 4; ++mt)
#pragma unroll
                for (int ks = 0; ks < 2; ++ks)
                    Aw[mt][ks] = *(const short8*)(wpk3 +
                        ((((tap * 4 + mt) * 2 + ks) * 64 + lane) << 3));
            short8 Bx[2][2];
#pragma unroll
            for (int nt = 0; nt < 2; ++nt) {
                int r = 2 * ohv[nt] - 1 + dr;
                int c = 2 * owv[nt] - 1 + dc;
                bool ok = (r >= 0) && (c >= 0);
                long long off = (((long long)bv[nt] * 16 + r) * 16 + c) * 64 + kg * 8;
#pragma unroll
                for (int ks = 0; ks < 2; ++ks) {
                    short8 z = {0, 0, 0, 0, 0, 0, 0, 0};
                    if (ok) z = *(const short8*)(pool2T + off + ks * 32);
                    Bx[nt][ks] = z;
                }
            }
#pragma unroll
            for (int ks = 0; ks < 2; ++ks)
#pragma unroll
                for (int nt = 0; nt < 2; ++nt)
#pragma unroll
                    for (int mt = 0; mt < 4; ++mt)
                        acc[mt][nt] = __builtin_amdgcn_mfma_f32_16x16x32_bf16(
                            Aw[mt][ks], Bx[nt][ks], acc[mt][nt], 0, 0, 0);
        }
    float4 bias4[4];
#pragma unroll
    for (int mt = 0; mt < 4; ++mt)
        bias4[mt] = *(const float4*)(bias3 + mt * 16 + kg * 4);
#pragma unroll
    for (int nt = 0; nt < 2; ++nt) {
        int pix = st * 32 + nt * 16 + n;
#pragma unroll
        for (int mt = 0; mt < 4; ++mt) {
            float v0 = acc[mt][nt][0] + bias4[mt].x; v0 = v0 > 0.f ? v0 : LEAKY * v0;
            float v1 = acc[mt][nt][1] + bias4[mt].y; v1 = v1 > 0.f ? v1 : LEAKY * v1;
            float v2 = acc[mt][nt][2] + bias4[mt].z; v2 = v2 > 0.f ? v2 : LEAKY * v2;
            float v3 = acc[mt][nt][3] + bias4[mt].w; v3 = v3 > 0.f ? v3 : LEAKY * v3;
            unsigned lo = bf16b(v0) | ((unsigned)bf16b(v1) << 16);
            unsigned hi = bf16b(v2) | ((unsigned)bf16b(v3) << 16);
            *(uint2*)(conv3T + pix * 64 + mt * 16 + kg * 4) = make_uint2(lo, hi);
        }
    }
}

// ---------- conv4 tail: pool3 -> conv4 -> mean -> FC ----------
__global__ __launch_bounds__(256) void conv4_k(const unsigned short* __restrict__ conv3T,
                                               const unsigned short* __restrict__ wpk4,
                                               const float* __restrict__ bias4p,
                                               const float* __restrict__ fcw,
                                               const float* __restrict__ fcb,
                                               float* __restrict__ R) {
    __shared__ unsigned short P3s[128 * 64];
    __shared__ float O4s[32 * 64];
    __shared__ float xsS[512];
    int tid = threadIdx.x, lane = tid & 63, wv = tid >> 6;
    int n = lane & 15, kg = lane >> 4;

    for (int i = 0; i < 4; ++i) {
        int task = i * 256 + tid;
        int cig = task & 7, idx = task >> 3;
        int bb = idx >> 4, y = (idx >> 2) & 3, x = idx & 3;
        float m[8];
#pragma unroll
        for (int j = 0; j < 8; ++j) m[j] = -1e30f;
#pragma unroll
        for (int r = 0; r < 2; ++r)
#pragma unroll
            for (int cx = 0; cx < 2; ++cx) {
                int sp = bb * 64 + (2 * y + r) * 8 + (2 * x + cx);
                short8 v = *(const short8*)(conv3T + sp * 64 + cig * 8);
#pragma unroll
                for (int j = 0; j < 8; ++j)
                    m[j] = fmaxf(m[j], b2f((unsigned short)v[j]));
            }
        short8 rv;
#pragma unroll
        for (int j = 0; j < 8; ++j)
            rv[j] = (short)(__builtin_bit_cast(unsigned, m[j]) >> 16);
        *(short8*)(P3s + idx * 64 + ((cig ^ (idx & 7)) << 3)) = rv;
    }
    __syncthreads();

    if (wv == 0) {
        f32x4 acc[4][2] = {};
        int bv[2], ohv[2], owv[2];
#pragma unroll
        for (int nt = 0; nt < 2; ++nt) {
            int p = nt * 16 + n;
            bv[nt] = p >> 2; ohv[nt] = (p >> 1) & 1; owv[nt] = p & 1;
        }
#pragma unroll
        for (int dr = 0; dr < 3; ++dr)
#pragma unroll
            for (int dc = 0; dc < 3; ++dc) {
                int tap = dr * 3 + dc;
                short8 Aw[4][2];
#pragma unroll
                for (int mt = 0; mt < 4; ++mt)
#pragma unroll
                    for (int ks = 0; ks < 2; ++ks)
                        Aw[mt][ks] = *(const short8*)(wpk4 +
                            ((((tap * 4 + mt) * 2 + ks) * 64 + lane) << 3));
                short8 Bx[2][2];
#pragma unroll
                for (int nt = 0; nt < 2; ++nt) {
                    int r = 2 * ohv[nt] - 1 + dr;
                    int c = 2 * owv[nt] - 1 + dc;
                    bool ok = (r >= 0) && (c >= 0);
                    int pix = bv[nt] * 16 + r * 4 + c;
#pragma unroll
                    for (int ks = 0; ks < 2; ++ks) {
                        short8 z = {0, 0, 0, 0, 0, 0, 0, 0};
                        if (ok) z = *(const short8*)(P3s + pix * 64 +
                                     (((ks * 4 + kg) ^ (pix & 7)) << 3));
                        Bx[nt][ks] = z;
                    }
                }
#pragma unroll
                for (int ks = 0; ks < 2; ++ks)
#pragma unroll
                    for (int nt = 0; nt < 2; ++nt)
#pragma unroll
                        for (int mt = 0; mt < 4; ++mt)
                            acc[mt][nt] = __builtin_amdgcn_mfma_f32_16x16x32_bf16(
                                Aw[mt][ks], Bx[nt][ks], acc[mt][nt], 0, 0, 0);
            }
        float4 bias4[4];
#pragma unroll
        for (int mt = 0; mt < 4; ++mt)
            bias4[mt] = *(const float4*)(bias4p + mt * 16 + kg * 4);
#pragma unroll
        for (int nt = 0; nt < 2; ++nt) {
            int p = nt * 16 + n;
#pragma unroll
            for (int mt = 0; mt < 4; ++mt) {
                float4 ov;
                float v0 = acc[mt][nt][0] + bias4[mt].x; ov.x = v0 > 0.f ? v0 : LEAKY * v0;
                float v1 = acc[mt][nt][1] + bias4[mt].y; ov.y = v1 > 0.f ? v1 : LEAKY * v1;
                float v2 = acc[mt][nt][2] + bias4[mt].z; ov.z = v2 > 0.f ? v2 : LEAKY * v2;
                float v3 = acc[mt][nt][3] + bias4[mt].w; ov.w = v3 > 0.f ? v3 : LEAKY * v3;
                *(float4*)(O4s + p * 64 + mt * 16 + kg * 4) = ov;
            }
        }
    }
    __syncthreads();

    for (int i = tid; i < 512; i += 256) {
        int bb = i >> 6, c = i & 63;
        xsS[i] = 0.25f * (O4s[(4 * bb + 0) * 64 + c] + O4s[(4 * bb + 1) * 64 + c] +
                          O4s[(4 * bb + 2) * 64 + c] + O4s[(4 * bb + 3) * 64 + c]);
    }
    __syncthreads();

#pragma unroll
    for (int k = 0; k < 20; ++k) {
        int o = k * 256 + tid;
        int bb = o / 640, i = o - bb * 640;
        float s = fcb[i];
        const float* wr = fcw + i * 64;
        const float* xb = xsS + bb * 64;
#pragma unroll 8
        for (int c = 0; c < 64; ++c) s += xb[c] * wr[c];
        R[o] = s;
    }
}

// ---------- out = feat + mask, ILP-4 float4 ----------
__global__ __launch_bounds__(256) void final_add_ilp(const float* __restrict__ feat,
                                                     const float* __restrict__ R,
                                                     float* __restrict__ out) {
    int bid = blockIdx.x;
    int q  = bid & 15;
    int bc = bid >> 4;
    int c = bc & 63, b = bc >> 6;
    int tid = threadIdx.x;
    int wq = tid & 63, rg = tid >> 6;
    int w0 = wq * 4;

    const float* Rp = R + (b * 640 + c * 10);
    float r0 = Rp[0], r1 = Rp[1], r2 = Rp[2], r3 = Rp[3], r4 = Rp[4];
    float r5 = Rp[5], r6 = Rp[6], r7 = Rp[7], r8 = Rp[8], r9 = Rp[9];

    float Lw[4], ej[4];
#pragma unroll
    for (int j = 0; j < 4; ++j) {
        Lw[j] = __builtin_amdgcn_logf((float)(w0 + j + 1) * (1.0f / 256.0f));
        ej[j] = (float)(255 - (w0 + j));
    }

    size_t base = ((size_t)(b * 64 + c)) * 65536;
    int h[4];
    float4 f[4];
#pragma unroll
    for (int k = 0; k < 4; ++k) {
        h[k] = q * 16 + k * 4 + rg;
        f[k] = *(const float4*)(feat + base + (size_t)h[k] * 256 + w0);
    }
#pragma unroll
    for (int k = 0; k < 4; ++k) {
        float Lh = __builtin_amdgcn_logf((float)(h[k] + 1) * (1.0f / 256.0f));
        float eh = (float)(255 - h[k]);
        float fv[4] = {f[k].x, f[k].y, f[k].z, f[k].w};
        float ov[4];
#pragma unroll
        for (int j = 0; j < 4; ++j) {
            float a  = __builtin_amdgcn_exp2f(ej[j] * Lh);   // x_h^(255-w)
            float bb = __builtin_amdgcn_exp2f(eh * Lw[j]);   // x_w^(255-h)
            float mask = (r9 + r3)
                       + bb * (r8 + bb * (r7 + bb * r6))
                       + a * ((r5 + bb * (r4 + bb * r3))
                              + a * (r2 + bb * r1 + a * r0));
            ov[j] = fv[j] + mask;
        }
        *(float4*)(out + base + (size_t)h[k] * 256 + w0) =
            make_float4(ov[0], ov[1], ov[2], ov[3]);
    }
}

extern "C" void kernel_launch(void* const* d_in, const int* in_sizes, int n_in,
                              void* d_out, int out_size, void* d_ws, size_t ws_size,
                              hipStream_t stream) {
    const float* feat = (const float*)d_in[0];
    const float* w1   = (const float*)d_in[1];
    const float* b1   = (const float*)d_in[2];
    const float* w2   = (const float*)d_in[3];
    const float* b2   = (const float*)d_in[4];
    const float* w3   = (const float*)d_in[5];
    const float* b3   = (const float*)d_in[6];
    const float* w4   = (const float*)d_in[7];
    const float* b4   = (const float*)d_in[8];
    const float* fcw  = (const float*)d_in[9];
    const float* fcb  = (const float*)d_in[10];
    float* out = (float*)d_out;

    // ws layout (ushort units)
    unsigned short* wsu    = (unsigned short*)d_ws;
    unsigned short* wpkAll = wsu;                        // 147456
    unsigned short* pool1T = wpkAll + 147456;            // 2097152
    unsigned short* pool2T = pool1T + 2097152;           // 131072
    unsigned short* conv3T = pool2T + 131072;            // 32768
    float*          Rm     = (float*)(conv3T + 32768);   // 5120 floats

    wpack_all<<<dim3(144, 4), 256, 0, stream>>>(w1, w2, w3, w4, wpkAll);
    conv1f<<<1024, 256, 0, stream>>>(feat, wpkAll, b1, pool1T);
    conv2_pool<<<128, 128, 0, stream>>>(pool1T, wpkAll + 36864, b2, pool2T);
    conv3_k<<<4, 256, 0, stream>>>(pool2T, wpkAll + 2 * 36864, b3, conv3T);
    conv4_k<<<1, 256, 0, stream>>>(conv3T, wpkAll + 3 * 36864, b4, fcw, fcb, Rm);
    final_add_ilp<<<8192, 256, 0, stream>>>(feat, Rm, out);
}

// Round 14
// 140.974 us; speedup vs baseline: 1.2820x; 1.0137x over previous
//
#include <hip/hip_runtime.h>
#include <hip/hip_bf16.h>
#include <cstddef>

#define LEAKY 0.01f

typedef short short8 __attribute__((ext_vector_type(8)));
typedef float f32x4 __attribute__((ext_vector_type(4)));

__device__ inline unsigned short bf16b(float f) {
    __hip_bfloat16 h = __float2bfloat16(f);   // RN
    return __builtin_bit_cast(unsigned short, h);
}
__device__ inline float b2f(unsigned short u) {
    unsigned v = (unsigned)u << 16;
    return __builtin_bit_cast(float, v);
}

// ---------- prepack all 4 conv weights into MFMA A-fragment order ----------
__global__ __launch_bounds__(256) void wpack_all(const float* __restrict__ w1,
                                                 const float* __restrict__ w2,
                                                 const float* __restrict__ w3,
                                                 const float* __restrict__ w4,
                                                 unsigned short* __restrict__ wpkAll) {
    const float* srcs[4] = {w1, w2, w3, w4};
    const float* w = srcs[blockIdx.y];
    unsigned short* wpk = wpkAll + blockIdx.y * 36864;
    int idx = blockIdx.x * 256 + threadIdx.x;   // 36864 = 9*4*2*64*8
    int j    = idx & 7;
    int lane = (idx >> 3) & 63;
    int rest = idx >> 9;
    int ks   = rest & 1;
    int mt   = (rest >> 1) & 3;
    int tap  = rest >> 3;
    int co = mt * 16 + (lane & 15);
    int ci = ks * 32 + (lane >> 4) * 8 + j;
    wpk[idx] = bf16b(w[(co * 64 + ci) * 9 + tap]);
}

// ---------- conv strip (NHWC bf16 input) for conv2 ----------
template<int IH, int IW>
__device__ inline void conv_strip(const unsigned short* __restrict__ inT,
                                  const unsigned short* __restrict__ wpk,
                                  int b, int row, int col0, int lane,
                                  f32x4 acc[4][2]) {
    int n = lane & 15, kg = lane >> 4;
#pragma unroll
    for (int dr = 0; dr < 3; ++dr) {
        int r = 2 * row - 1 + dr;
        if (r < 0) continue;
        const unsigned short* rowp = inT + (((size_t)b * IH + r) * IW) * 64 + kg * 8;
#pragma unroll
        for (int dc = 0; dc < 3; ++dc) {
            int tap = dr * 3 + dc;
            short8 Aw[4][2];
#pragma unroll
            for (int mt = 0; mt < 4; ++mt)
#pragma unroll
                for (int ks = 0; ks < 2; ++ks)
                    Aw[mt][ks] = *(const short8*)(wpk +
                        ((((tap * 4 + mt) * 2 + ks) * 64 + lane) << 3));
            short8 Bx[2][2];
#pragma unroll
            for (int nt = 0; nt < 2; ++nt) {
                int c = 2 * (col0 + nt * 16 + n) - 1 + dc;
                bool ok = c >= 0;
                const unsigned short* p = rowp + (long long)c * 64;
#pragma unroll
                for (int ks = 0; ks < 2; ++ks) {
                    short8 z = {0, 0, 0, 0, 0, 0, 0, 0};
                    if (ok) z = *(const short8*)(p + ks * 32);
                    Bx[nt][ks] = z;
                }
            }
#pragma unroll
            for (int ks = 0; ks < 2; ++ks)
#pragma unroll
                for (int nt = 0; nt < 2; ++nt)
#pragma unroll
                    for (int mt = 0; mt < 4; ++mt)
                        acc[mt][nt] = __builtin_amdgcn_mfma_f32_16x16x32_bf16(
                            Aw[mt][ks], Bx[nt][ks], acc[mt][nt], 0, 0, 0);
        }
    }
}

// epilogue: bias + leaky -> bf16, swizzled 8B stores into LDS tile
__device__ inline void epi_to_lds(f32x4 acc[4][2], const float* __restrict__ bias,
                                  unsigned short* Ls, int pixbase, int lane) {
    int n = lane & 15, kg = lane >> 4;
    float4 bias4[4];
#pragma unroll
    for (int mt = 0; mt < 4; ++mt)
        bias4[mt] = *(const float4*)(bias + mt * 16 + kg * 4);
#pragma unroll
    for (int nt = 0; nt < 2; ++nt) {
        int pix = pixbase + nt * 16 + n;
#pragma unroll
        for (int mt = 0; mt < 4; ++mt) {
            float v0 = acc[mt][nt][0] + bias4[mt].x; v0 = v0 > 0.f ? v0 : LEAKY * v0;
            float v1 = acc[mt][nt][1] + bias4[mt].y; v1 = v1 > 0.f ? v1 : LEAKY * v1;
            float v2 = acc[mt][nt][2] + bias4[mt].z; v2 = v2 > 0.f ? v2 : LEAKY * v2;
            float v3 = acc[mt][nt][3] + bias4[mt].w; v3 = v3 > 0.f ? v3 : LEAKY * v3;
            unsigned lo = bf16b(v0) | ((unsigned)bf16b(v1) << 16);
            unsigned hi = bf16b(v2) | ((unsigned)bf16b(v3) << 16);
            int g = mt * 2 + (kg >> 1);
            *(uint2*)(Ls + pix * 64 + (((g ^ (pix & 7)) << 3) + (kg & 1) * 4)) =
                make_uint2(lo, hi);
        }
    }
}

__device__ inline short8 lds_granule(const unsigned short* Ls, int pix, int cig) {
    return *(const short8*)(Ls + pix * 64 + ((cig ^ (pix & 7)) << 3));
}

// ---------- conv1 fused (r13 structure + 8-deep load batch): NCHW f32 -> conv+lrelu -> pool ----------
// Single Trow tile (16.6 KB LDS, reused for pool), 2 barriers/row. ONLY change
// vs r13: the stage loop issues all 8 float4 loads (+edge) into registers
// BEFORE any cvt/ds_write -> per-thread MLP 1 -> 8. Nothing live across MFMA.
__global__ __launch_bounds__(256, 4) void conv1f(const float* __restrict__ feat,
                                                 const unsigned short* __restrict__ wpk,
                                                 const float* __restrict__ bias,
                                                 unsigned short* __restrict__ poolT) {
    __shared__ unsigned short Trow[130 * 64];   // 16640 B; reused as pool tile
    int o = blockIdx.x;
    int blk = (o & 7) * 128 + (o >> 3);         // XCD-bijective
    int half = blk & 1, ohp = (blk >> 1) & 63, b = blk >> 7;
    int tid = threadIdx.x, lane = tid & 63, wv = tid >> 6;
    int n = lane & 15, kg = lane >> 4;
    int c0h = half * 64;                        // block's output-col base
    int colw = (wv & 1) * 32;                   // wave's col offset in block
    int row_wv = 2 * ohp + (wv >> 1);           // wave's conv output row

    f32x4 acc[4][2] = {};

    int ci0 = tid >> 5, colq = tid & 31;
    const float* fb = feat + (size_t)(b * 64) * 65536;

    for (int r = 4 * ohp - 1; r <= 4 * ohp + 3; ++r) {
        if (r < 0) continue;                    // block-uniform
        __syncthreads();                        // Trow free of prior readers
        // ---- stage row r: issue ALL loads first (MLP=8+1), then cvt+write ----
        const float* rp = fb + (size_t)r * 256 + 2 * c0h + colq * 4;
        float4 t[8];
#pragma unroll
        for (int k = 0; k < 8; ++k)
            t[k] = *(const float4*)(rp + (size_t)(ci0 + k * 8) * 65536);
        float ev = 0.f;
        if (tid < 64 && c0h != 0)
            ev = fb[(size_t)tid * 65536 + (size_t)r * 256 + 2 * c0h - 1];
#pragma unroll
        for (int k = 0; k < 8; ++k) {
            int cci = ci0 + k * 8;
            float fv[4] = {t[k].x, t[k].y, t[k].z, t[k].w};
#pragma unroll
            for (int j = 0; j < 4; ++j) {
                int slot = colq * 4 + j + 1;
                int pos = (cci >> 3) ^ ((slot >> 2) & 7);
                Trow[slot * 64 + pos * 8 + (cci & 7)] = bf16b(fv[j]);
            }
        }
        // ---- edge slot 0 = input col 2*c0h-1 (zeros when half==0) ----
        if (tid < 64)
            Trow[(tid >> 3) * 8 + (tid & 7)] = bf16b(ev);
        __syncthreads();
        // ---- MFMA: this wave uses row r iff dr in [0,2] ----
        int dr = r - 2 * row_wv + 1;
        if (dr < 0 || dr > 2) continue;         // wave-uniform
#pragma unroll
        for (int dc = 0; dc < 3; ++dc) {
            int tap = dr * 3 + dc;
            short8 Aw[4][2];
#pragma unroll
            for (int mt = 0; mt < 4; ++mt)
#pragma unroll
                for (int ks = 0; ks < 2; ++ks)
                    Aw[mt][ks] = *(const short8*)(wpk +
                        ((((tap * 4 + mt) * 2 + ks) * 64 + lane) << 3));
            short8 Bx[2][2];
#pragma unroll
            for (int nt = 0; nt < 2; ++nt) {
                int slot = 2 * (colw + nt * 16 + n) + dc;   // 0..128
#pragma unroll
                for (int ks = 0; ks < 2; ++ks) {
                    int g = ks * 4 + kg;
                    int pos = g ^ ((slot >> 2) & 7);
                    Bx[nt][ks] = *(const short8*)(Trow + slot * 64 + pos * 8);
                }
            }
#pragma unroll
            for (int ks = 0; ks < 2; ++ks)
#pragma unroll
                for (int nt = 0; nt < 2; ++nt)
#pragma unroll
                    for (int mt = 0; mt < 4; ++mt)
                        acc[mt][nt] = __builtin_amdgcn_mfma_f32_16x16x32_bf16(
                            Aw[mt][ks], Bx[nt][ks], acc[mt][nt], 0, 0, 0);
        }
    }

    // ---- epilogue + pool, reusing Trow as the tile ----
    __syncthreads();                            // all MFMA reads of Trow done
    epi_to_lds(acc, bias, Trow, (wv >> 1) * 64 + colw, lane);
    __syncthreads();

    int px = tid >> 3, cig = tid & 7;
    float m[8];
#pragma unroll
    for (int j = 0; j < 8; ++j) m[j] = -1e30f;
#pragma unroll
    for (int r = 0; r < 2; ++r)
#pragma unroll
        for (int cx = 0; cx < 2; ++cx) {
            short8 v = lds_granule(Trow, r * 64 + 2 * px + cx, cig);
#pragma unroll
            for (int j = 0; j < 8; ++j)
                m[j] = fmaxf(m[j], b2f((unsigned short)v[j]));
        }
    short8 rv;
#pragma unroll
    for (int j = 0; j < 8; ++j)
        rv[j] = (short)(__builtin_bit_cast(unsigned, m[j]) >> 16);
    *(short8*)(poolT + (((size_t)(b * 64 + ohp) * 64) + half * 32 + px) * 64 + cig * 8) = rv;
}

// ---------- conv2 (64->32) + pool (->16): 128 blocks x 128 thr ----------
__global__ __launch_bounds__(128) void conv2_pool(const unsigned short* __restrict__ inT,
                                                  const unsigned short* __restrict__ wpk,
                                                  const float* __restrict__ bias,
                                                  unsigned short* __restrict__ poolT) {
    __shared__ unsigned short Ls[64 * 64];     // 8 KB
    int o = blockIdx.x;
    int blk = (o & 7) * 16 + (o >> 3);
    int q = blk & 15, b = blk >> 4;
    int tid = threadIdx.x, lane = tid & 63, wv = tid >> 6;

    int row = 2 * q + wv;
    f32x4 acc[4][2] = {};
    conv_strip<64, 64>(inT, wpk, b, row, 0, lane, acc);
    epi_to_lds(acc, bias, Ls, wv * 32, lane);
    __syncthreads();

    int px = tid >> 3, cig = tid & 7;
    float m[8];
#pragma unroll
    for (int j = 0; j < 8; ++j) m[j] = -1e30f;
#pragma unroll
    for (int r = 0; r < 2; ++r)
#pragma unroll
        for (int cx = 0; cx < 2; ++cx) {
            short8 v = lds_granule(Ls, r * 32 + 2 * px + cx, cig);
#pragma unroll
            for (int j = 0; j < 8; ++j)
                m[j] = fmaxf(m[j], b2f((unsigned short)v[j]));
        }
    short8 rv;
#pragma unroll
    for (int j = 0; j < 8; ++j)
        rv[j] = (short)(__builtin_bit_cast(unsigned, m[j]) >> 16);
    *(short8*)(poolT + (((size_t)(b * 16 + q) * 16) + px) * 64 + cig * 8) = rv;
}

// ---------- conv3 (16->8): 4 blocks x 4 waves ----------
__global__ __launch_bounds__(256) void conv3_k(const unsigned short* __restrict__ pool2T,
                                               const unsigned short* __restrict__ wpk3,
                                               const float* __restrict__ bias3,
                                               unsigned short* __restrict__ conv3T) {
    int tid = threadIdx.x, lane = tid & 63, wv = tid >> 6;
    int n = lane & 15, kg = lane >> 4;
    int st = blockIdx.x * 4 + wv;
    f32x4 acc[4][2] = {};
    int bv[2], ohv[2], owv[2];
#pragma unroll
    for (int nt = 0; nt < 2; ++nt) {
        int p = st * 32 + nt * 16 + n;
        bv[nt] = p >> 6; ohv[nt] = (p >> 3) & 7; owv[nt] = p & 7;
    }
#pragma unroll
    for (int dr = 0; dr < 3; ++dr)
#pragma unroll
        for (int dc = 0; dc < 3; ++dc) {
            int tap = dr * 3 + dc;
            short8 Aw[4][2];
#pragma unroll
            for (int mt = 0; mt < 4; ++mt)
#pragma unroll
                for (int ks = 0; ks < 2; ++ks)
                    Aw[mt][ks] = *(const short8*)(wpk3 +
                        ((((tap * 4 + mt) * 2 + ks) * 64 + lane) << 3));
            short8 Bx[2][2];
#pragma unroll
            for (int nt = 0; nt < 2; ++nt) {
                int r = 2 * ohv[nt] - 1 + dr;
                int c = 2 * owv[nt] - 1 + dc;
                bool ok = (r >= 0) && (c >= 0);
                long long off = (((long long)bv[nt] * 16 + r) * 16 + c) * 64 + kg * 8;
#pragma unroll
                for (int ks = 0; ks < 2; ++ks) {
                    short8 z = {0, 0, 0, 0, 0, 0, 0, 0};
                    if (ok) z = *(const short8*)(pool2T + off + ks * 32);
                    Bx[nt][ks] = z;
                }
            }
#pragma unroll
            for (int ks = 0; ks < 2; ++ks)
#pragma unroll
                for (int nt = 0; nt < 2; ++nt)
#pragma unroll
                    for (int mt = 0; mt < 4; ++mt)
                        acc[mt][nt] = __builtin_amdgcn_mfma_f32_16x16x32_bf16(
                            Aw[mt][ks], Bx[nt][ks], acc[mt][nt], 0, 0, 0);
        }
    float4 bias4[4];
#pragma unroll
    for (int mt = 0; mt < 4; ++mt)
        bias4[mt] = *(const float4*)(bias3 + mt * 16 + kg * 4);
#pragma unroll
    for (int nt = 0; nt < 2; ++nt) {
        int pix = st * 32 + nt * 16 + n;
#pragma unroll
        for (int mt = 0; mt < 4; ++mt) {
            float v0 = acc[mt][nt][0] + bias4[mt].x; v0 = v0 > 0.f ? v0 : LEAKY * v0;
            float v1 = acc[mt][nt][1] + bias4[mt].y; v1 = v1 > 0.f ? v1 : LEAKY * v1;
            float v2 = acc[mt][nt][2] + bias4[mt].z; v2 = v2 > 0.f ? v2 : LEAKY * v2;
            float v3 = acc[mt][nt][3] + bias4[mt].w; v3 = v3 > 0.f ? v3 : LEAKY * v3;
            unsigned lo = bf16b(v0) | ((unsigned)bf16b(v1) << 16);
            unsigned hi = bf16b(v2) | ((unsigned)bf16b(v3) << 16);
            *(uint2*)(conv3T + pix * 64 + mt * 16 + kg * 4) = make_uint2(lo, hi);
        }
    }
}

// ---------- conv4 tail: pool3 -> conv4 -> mean -> FC ----------
__global__ __launch_bounds__(256) void conv4_k(const unsigned short* __restrict__ conv3T,
                                               const unsigned short* __restrict__ wpk4,
                                               const float* __restrict__ bias4p,
                                               const float* __restrict__ fcw,
                                               const float* __restrict__ fcb,
                                               float* __restrict__ R) {
    __shared__ unsigned short P3s[128 * 64];
    __shared__ float O4s[32 * 64];
    __shared__ float xsS[512];
    int tid = threadIdx.x, lane = tid & 63, wv = tid >> 6;
    int n = lane & 15, kg = lane >> 4;

    for (int i = 0; i < 4; ++i) {
        int task = i * 256 + tid;
        int cig = task & 7, idx = task >> 3;
        int bb = idx >> 4, y = (idx >> 2) & 3, x = idx & 3;
        float m[8];
#pragma unroll
        for (int j = 0; j < 8; ++j) m[j] = -1e30f;
#pragma unroll
        for (int r = 0; r < 2; ++r)
#pragma unroll
            for (int cx = 0; cx < 2; ++cx) {
                int sp = bb * 64 + (2 * y + r) * 8 + (2 * x + cx);
                short8 v = *(const short8*)(conv3T + sp * 64 + cig * 8);
#pragma unroll
                for (int j = 0; j < 8; ++j)
                    m[j] = fmaxf(m[j], b2f((unsigned short)v[j]));
            }
        short8 rv;
#pragma unroll
        for (int j = 0; j < 8; ++j)
            rv[j] = (short)(__builtin_bit_cast(unsigned, m[j]) >> 16);
        *(short8*)(P3s + idx * 64 + ((cig ^ (idx & 7)) << 3)) = rv;
    }
    __syncthreads();

    if (wv == 0) {
        f32x4 acc[4][2] = {};
        int bv[2], ohv[2], owv[2];
#pragma unroll
        for (int nt = 0; nt < 2; ++nt) {
            int p = nt * 16 + n;
            bv[nt] = p >> 2; ohv[nt] = (p >> 1) & 1; owv[nt] = p & 1;
        }
#pragma unroll
        for (int dr = 0; dr < 3; ++dr)
#pragma unroll
            for (int dc = 0; dc < 3; ++dc) {
                int tap = dr * 3 + dc;
                short8 Aw[4][2];
#pragma unroll
                for (int mt = 0; mt < 4; ++mt)
#pragma unroll
                    for (int ks = 0; ks < 2; ++ks)
                        Aw[mt][ks] = *(const short8*)(wpk4 +
                            ((((tap * 4 + mt) * 2 + ks) * 64 + lane) << 3));
                short8 Bx[2][2];
#pragma unroll
                for (int nt = 0; nt < 2; ++nt) {
                    int r = 2 * ohv[nt] - 1 + dr;
                    int c = 2 * owv[nt] - 1 + dc;
                    bool ok = (r >= 0) && (c >= 0);
                    int pix = bv[nt] * 16 + r * 4 + c;
#pragma unroll
                    for (int ks = 0; ks < 2; ++ks) {
                        short8 z = {0, 0, 0, 0, 0, 0, 0, 0};
                        if (ok) z = *(const short8*)(P3s + pix * 64 +
                                     (((ks * 4 + kg) ^ (pix & 7)) << 3));
                        Bx[nt][ks] = z;
                    }
                }
#pragma unroll
                for (int ks = 0; ks < 2; ++ks)
#pragma unroll
                    for (int nt = 0; nt < 2; ++nt)
#pragma unroll
                        for (int mt = 0; mt < 4; ++mt)
                            acc[mt][nt] = __builtin_amdgcn_mfma_f32_16x16x32_bf16(
                                Aw[mt][ks], Bx[nt][ks], acc[mt][nt], 0, 0, 0);
            }
        float4 bias4[4];
#pragma unroll
        for (int mt = 0; mt < 4; ++mt)
            bias4[mt] = *(const float4*)(bias4p + mt * 16 + kg * 4);
#pragma unroll
        for (int nt = 0; nt < 2; ++nt) {
            int p = nt * 16 + n;
#pragma unroll
            for (int mt = 0; mt < 4; ++mt) {
                float4 ov;
                float v0 = acc[mt][nt][0] + bias4[mt].x; ov.x = v0 > 0.f ? v0 : LEAKY * v0;
                float v1 = acc[mt][nt][1] + bias4[mt].y; ov.y = v1 > 0.f ? v1 : LEAKY * v1;
                float v2 = acc[mt][nt][2] + bias4[mt].z; ov.z = v2 > 0.f ? v2 : LEAKY * v2;
                float v3 = acc[mt][nt][3] + bias4[mt].w; ov.w = v3 > 0.f ? v3 : LEAKY * v3;
                *(float4*)(O4s + p * 64 + mt * 16 + kg * 4) = ov;
            }
        }
    }
    __syncthreads();

    for (int i = tid; i < 512; i += 256) {
        int bb = i >> 6, c = i & 63;
        xsS[i] = 0.25f * (O4s[(4 * bb + 0) * 64 + c] + O4s[(4 * bb + 1) * 64 + c] +
                          O4s[(4 * bb + 2) * 64 + c] + O4s[(4 * bb + 3) * 64 + c]);
    }
    __syncthreads();

#pragma unroll
    for (int k = 0; k < 20; ++k) {
        int o = k * 256 + tid;
        int bb = o / 640, i = o - bb * 640;
        float s = fcb[i];
        const float* wr = fcw + i * 64;
        const float* xb = xsS + bb * 64;
#pragma unroll 8
        for (int c = 0; c < 64; ++c) s += xb[c] * wr[c];
        R[o] = s;
    }
}

// ---------- out = feat + mask, ILP-4 float4 ----------
__global__ __launch_bounds__(256) void final_add_ilp(const float* __restrict__ feat,
                                                     const float* __restrict__ R,
                                                     float* __restrict__ out) {
    int bid = blockIdx.x;
    int q  = bid & 15;
    int bc = bid >> 4;
    int c = bc & 63, b = bc >> 6;
    int tid = threadIdx.x;
    int wq = tid & 63, rg = tid >> 6;
    int w0 = wq * 4;

    const float* Rp = R + (b * 640 + c * 10);
    float r0 = Rp[0], r1 = Rp[1], r2 = Rp[2], r3 = Rp[3], r4 = Rp[4];
    float r5 = Rp[5], r6 = Rp[6], r7 = Rp[7], r8 = Rp[8], r9 = Rp[9];

    float Lw[4], ej[4];
#pragma unroll
    for (int j = 0; j < 4; ++j) {
        Lw[j] = __builtin_amdgcn_logf((float)(w0 + j + 1) * (1.0f / 256.0f));
        ej[j] = (float)(255 - (w0 + j));
    }

    size_t base = ((size_t)(b * 64 + c)) * 65536;
    int h[4];
    float4 f[4];
#pragma unroll
    for (int k = 0; k < 4; ++k) {
        h[k] = q * 16 + k * 4 + rg;
        f[k] = *(const float4*)(feat + base + (size_t)h[k] * 256 + w0);
    }
#pragma unroll
    for (int k = 0; k < 4; ++k) {
        float Lh = __builtin_amdgcn_logf((float)(h[k] + 1) * (1.0f / 256.0f));
        float eh = (float)(255 - h[k]);
        float fv[4] = {f[k].x, f[k].y, f[k].z, f[k].w};
        float ov[4];
#pragma unroll
        for (int j = 0; j < 4; ++j) {
            float a  = __builtin_amdgcn_exp2f(ej[j] * Lh);   // x_h^(255-w)
            float bb = __builtin_amdgcn_exp2f(eh * Lw[j]);   // x_w^(255-h)
            float mask = (r9 + r3)
                       + bb * (r8 + bb * (r7 + bb * r6))
                       + a * ((r5 + bb * (r4 + bb * r3))
                              + a * (r2 + bb * r1 + a * r0));
            ov[j] = fv[j] + mask;
        }
        *(float4*)(out + base + (size_t)h[k] * 256 + w0) =
            make_float4(ov[0], ov[1], ov[2], ov[3]);
    }
}

extern "C" void kernel_launch(void* const* d_in, const int* in_sizes, int n_in,
                              void* d_out, int out_size, void* d_ws, size_t ws_size,
                              hipStream_t stream) {
    const float* feat = (const float*)d_in[0];
    const float* w1   = (const float*)d_in[1];
    const float* b1   = (const float*)d_in[2];
    const float* w2   = (const float*)d_in[3];
    const float* b2   = (const float*)d_in[4];
    const float* w3   = (const float*)d_in[5];
    const float* b3   = (const float*)d_in[6];
    const float* w4   = (const float*)d_in[7];
    const float* b4   = (const float*)d_in[8];
    const float* fcw  = (const float*)d_in[9];
    const float* fcb  = (const float*)d_in[10];
    float* out = (float*)d_out;

    // ws layout (ushort units)
    unsigned short* wsu    = (unsigned short*)d_ws;
    unsigned short* wpkAll = wsu;                        // 147456
    unsigned short* pool1T = wpkAll + 147456;            // 2097152
    unsigned short* pool2T = pool1T + 2097152;           // 131072
    unsigned short* conv3T = pool2T + 131072;            // 32768
    float*          Rm     = (float*)(conv3T + 32768);   // 5120 floats

    wpack_all<<<dim3(144, 4), 256, 0, stream>>>(w1, w2, w3, w4, wpkAll);
    conv1f<<<1024, 256, 0, stream>>>(feat, wpkAll, b1, pool1T);
    conv2_pool<<<128, 128, 0, stream>>>(pool1T, wpkAll + 36864, b2, pool2T);
    conv3_k<<<4, 256, 0, stream>>>(pool2T, wpkAll + 2 * 36864, b3, conv3T);
    conv4_k<<<1, 256, 0, stream>>>(conv3T, wpkAll + 3 * 36864, b4, fcw, fcb, Rm);
    final_add_ilp<<<8192, 256, 0, stream>>>(feat, Rm, out);
}